// Round 4
// baseline (1768.869 us; speedup 1.0000x reference)
//
#include <hip/hip_runtime.h>

// ---------------------------------------------------------------------------
// GCN via bucket-grained CSR (128 nodes/bucket) — all per-edge atomics in LDS.
//   hs = dinv[row] * (in @ W)            (GEMM, row-scale fused)
//   agg_i = dinv_i * ( hs_i + sum_{src->i} hs_src )
//   h1 = Agg(x@W1); h2 = Agg(relu(h1+b1)@W2); out = mean(relu(h2+b2))@Wfc+bfc
// Packed edge word: (dst & 127) << 17 | src   (needs N <= 131072).
// edge_index arrives as int32 (harness converts integer inputs).
// ---------------------------------------------------------------------------

#define NSB 512  // scatter blocks

// per-(scatterblock, bucket) histogram; no global atomics
__global__ __launch_bounds__(256) void k_bcount(const int* __restrict__ dst,
                                                unsigned* __restrict__ cntBB,
                                                int E, int nbuk, int chunk) {
    __shared__ unsigned hist[1024];
    for (int i = threadIdx.x; i < nbuk; i += 256) hist[i] = 0u;
    __syncthreads();
    int lo = blockIdx.x * chunk, hi = min(E, lo + chunk);
    for (int e = lo + threadIdx.x; e < hi; e += 256)
        atomicAdd(&hist[((unsigned)dst[e]) >> 7], 1u);
    __syncthreads();
    for (int i = threadIdx.x; i < nbuk; i += 256)
        cntBB[(size_t)blockIdx.x * nbuk + i] = hist[i];
}

// bbase[k] = exclusive scan over buckets of total counts; bbase[nbuk] = E
__global__ __launch_bounds__(1024) void k_bucket_base(const unsigned* __restrict__ cntBB,
                                                      unsigned* __restrict__ bbase,
                                                      int nbuk, int nsb) {
    __shared__ unsigned s[1024];
    int k = threadIdx.x;
    unsigned v = 0u;
    if (k < nbuk)
        for (int b = 0; b < nsb; ++b) v += cntBB[(size_t)b * nbuk + k];
    s[k] = v;
    __syncthreads();
    for (int off = 1; off < 1024; off <<= 1) {
        unsigned a = (k >= off) ? s[k - off] : 0u;
        __syncthreads();
        s[k] += a;
        __syncthreads();
    }
    if (k < nbuk) bbase[k] = s[k] - v;          // exclusive
    if (k == 0) bbase[nbuk] = s[1023];          // total = E
}

// in-place: cntBB[t][k] -> bbase[k] + exclusive scan over scatter-blocks t
__global__ __launch_bounds__(NSB) void k_block_base(unsigned* __restrict__ cntBB,
                                                    const unsigned* __restrict__ bbase,
                                                    int nbuk) {
    __shared__ unsigned s[NSB];
    int k = blockIdx.x;
    int t = threadIdx.x;
    unsigned v = cntBB[(size_t)t * nbuk + k];
    s[t] = v;
    __syncthreads();
    for (int off = 1; off < NSB; off <<= 1) {
        unsigned a = (t >= off) ? s[t - off] : 0u;
        __syncthreads();
        s[t] += a;
        __syncthreads();
    }
    cntBB[(size_t)t * nbuk + k] = bbase[k] + s[t] - v;
}

// scatter packed edges; cursors live in LDS
__global__ __launch_bounds__(256) void k_bscatter(const int* __restrict__ src,
                                                  const int* __restrict__ dst,
                                                  const unsigned* __restrict__ baseBB,
                                                  unsigned* __restrict__ epk,
                                                  int E, int nbuk, int chunk) {
    __shared__ unsigned cur[1024];
    for (int i = threadIdx.x; i < nbuk; i += 256)
        cur[i] = baseBB[(size_t)blockIdx.x * nbuk + i];
    __syncthreads();
    int lo = blockIdx.x * chunk, hi = min(E, lo + chunk);
    for (int e = lo + threadIdx.x; e < hi; e += 256) {
        unsigned d = (unsigned)dst[e];
        unsigned s = (unsigned)src[e];
        unsigned pos = atomicAdd(&cur[d >> 7], 1u);
        epk[pos] = ((d & 127u) << 17) | s;
    }
}

// per-bucket degree count -> dinv = rsqrt(1+deg)
__global__ __launch_bounds__(256) void k_degrees(const unsigned* __restrict__ bbase,
                                                 const unsigned* __restrict__ epk,
                                                 float* __restrict__ dinv, int N) {
    __shared__ unsigned dcnt[128];
    int k = blockIdx.x;
    if (threadIdx.x < 128) dcnt[threadIdx.x] = 0u;
    __syncthreads();
    unsigned lo = bbase[k], hi = bbase[k + 1];
    for (unsigned e = lo + threadIdx.x; e < hi; e += 256)
        atomicAdd(&dcnt[epk[e] >> 17], 1u);
    __syncthreads();
    int node = (k << 7) + threadIdx.x;
    if (threadIdx.x < 128 && node < N)
        dinv[node] = rsqrtf(1.0f + (float)dcnt[threadIdx.x]);
}

// out[row][j] = rowscale[row] * sum_i f(in[row][i]) * W[i][j];  f=relu(v+bias) if relu_in
__global__ __launch_bounds__(256) void k_gemm64(const float* __restrict__ in,
                                                const float* __restrict__ W,
                                                const float* __restrict__ bias, int relu_in,
                                                const float* __restrict__ rowscale,
                                                float* __restrict__ out, int N) {
    __shared__ float Wl[64 * 64];
    for (int i = threadIdx.x; i < 64 * 64; i += 256) Wl[i] = W[i];
    __syncthreads();
    const int lane = threadIdx.x & 63;
    const int wave = threadIdx.x >> 6;
    const float bv = relu_in ? bias[lane] : 0.0f;
    for (int row = blockIdx.x * 4 + wave; row < N; row += gridDim.x * 4) {
        float x = in[(size_t)row * 64 + lane];
        if (relu_in) x = fmaxf(x + bv, 0.0f);
        float acc = 0.0f;
#pragma unroll
        for (int i = 0; i < 64; ++i)
            acc = fmaf(__shfl(x, i), Wl[i * 64 + lane], acc);
        out[(size_t)row * 64 + lane] = acc * rowscale[row];
    }
}

// bucketed aggregate: LDS acc[128][66]; 1 coalesced row-gather + 1 LDS f32 add per edge
__global__ __launch_bounds__(512) void k_agg_buk(const float* __restrict__ hs,
                                                 const float* __restrict__ dinv,
                                                 const unsigned* __restrict__ bbase,
                                                 const unsigned* __restrict__ epk,
                                                 float* __restrict__ out, int N) {
    __shared__ float acc[128 * 66];
    const int k = blockIdx.x;
    const int node0 = k << 7;
    const int nn = min(128, N - node0);
    const int lane = threadIdx.x & 63;
    const int wv = threadIdx.x >> 6;  // 8 waves
    for (int idx = threadIdx.x; idx < (nn << 6); idx += 512) {
        int r = idx >> 6, c = idx & 63;
        acc[r * 66 + c] = hs[(size_t)(node0 + r) * 64 + c];   // self-loop init
    }
    __syncthreads();
    const unsigned lo = bbase[k], hi = bbase[k + 1];
    for (unsigned base = lo + (unsigned)wv * 64u; base < hi; base += 512u) {
        unsigned myE = (base + lane < hi) ? epk[base + lane] : 0u;
        int cnt = (int)min(64u, hi - base);
        if (cnt == 64) {
#pragma unroll 4
            for (int j = 0; j < 64; ++j) {
                unsigned ew = __shfl(myE, j);
                float v = hs[(size_t)(ew & 0x1FFFFu) * 64 + lane];
                atomicAdd(&acc[(ew >> 17) * 66 + lane], v);
            }
        } else {
            for (int j = 0; j < cnt; ++j) {
                unsigned ew = __shfl(myE, j);
                float v = hs[(size_t)(ew & 0x1FFFFu) * 64 + lane];
                atomicAdd(&acc[(ew >> 17) * 66 + lane], v);
            }
        }
    }
    __syncthreads();
    for (int idx = threadIdx.x; idx < (nn << 6); idx += 512) {
        int r = idx >> 6, c = idx & 63;
        out[(size_t)(node0 + r) * 64 + c] = dinv[node0 + r] * acc[r * 66 + c];
    }
}

// colsum[j] = sum_rows relu(in[row][j] + bias[j])
__global__ __launch_bounds__(256) void k_colsum(const float* __restrict__ in,
                                                const float* __restrict__ bias,
                                                float* __restrict__ colsum, int N) {
    const int lane = threadIdx.x & 63;
    const int wave = threadIdx.x >> 6;
    const float bv = bias[lane];
    float acc = 0.0f;
    for (int row = blockIdx.x * 4 + wave; row < N; row += gridDim.x * 4)
        acc += fmaxf(in[(size_t)row * 64 + lane] + bv, 0.0f);
    __shared__ float red[4][64];
    red[wave][lane] = acc;
    __syncthreads();
    if (wave == 0)
        unsafeAtomicAdd(&colsum[lane],
                        red[0][lane] + red[1][lane] + red[2][lane] + red[3][lane]);
}

// out[j] = (colsum/N) @ Wfc + bfc
__global__ void k_final(const float* __restrict__ colsum, const float* __restrict__ Wfc,
                        const float* __restrict__ bfc, float* __restrict__ out, float invN) {
    int j = threadIdx.x;  // 64 threads
    float acc = 0.0f;
#pragma unroll
    for (int i = 0; i < 64; ++i)
        acc = fmaf(colsum[i] * invN, Wfc[i * 64 + j], acc);
    out[j] = acc + bfc[j];
}

extern "C" void kernel_launch(void* const* d_in, const int* in_sizes, int n_in,
                              void* d_out, int out_size, void* d_ws, size_t ws_size,
                              hipStream_t stream) {
    const float* x   = (const float*)d_in[0];
    const int*   ei  = (const int*)d_in[1];
    const float* W1  = (const float*)d_in[2];
    const float* b1  = (const float*)d_in[3];
    const float* W2  = (const float*)d_in[4];
    const float* b2  = (const float*)d_in[5];
    const float* Wfc = (const float*)d_in[6];
    const float* bfc = (const float*)d_in[7];
    float*       out = (float*)d_out;

    const int N = in_sizes[0] / 64;
    const int E = in_sizes[1] / 2;
    const int* src = ei;       // edge_index[0]
    const int* dst = ei + E;   // edge_index[1]

    const int nbuk  = (N + 127) >> 7;              // 782
    const int chunk = (E + NSB - 1) / NSB;         // 3125

    char* ws = (char*)d_ws;
    const size_t NB = (size_t)N * 64 * sizeof(float);             // 25.6 MB
    float*    bufA  = (float*)ws;
    float*    bufB  = (float*)(ws + NB);
    unsigned* cntBB = (unsigned*)ws;               // aliases bufA (dead before GEMM1)
    const size_t N4 = (((size_t)N * 4) + 255) & ~(size_t)255;
    float*    dinv  = (float*)(ws + 2 * NB);
    unsigned* bbase = (unsigned*)(ws + 2 * NB + N4);
    unsigned* epk   = (unsigned*)(ws + 2 * NB + N4 + 4096);
    float*    csum  = (float*)(ws + 2 * NB + N4 + 4096 +
                               ((((size_t)E * 4) + 255) & ~(size_t)255));

    // ---- bucket-CSR build (all per-edge atomics in LDS) ----
    k_bcount<<<NSB, 256, 0, stream>>>(dst, cntBB, E, nbuk, chunk);
    k_bucket_base<<<1, 1024, 0, stream>>>(cntBB, bbase, nbuk, NSB);
    k_block_base<<<nbuk, NSB, 0, stream>>>(cntBB, bbase, nbuk);
    k_bscatter<<<NSB, 256, 0, stream>>>(src, dst, cntBB, epk, E, nbuk, chunk);
    k_degrees<<<nbuk, 256, 0, stream>>>(bbase, epk, dinv, N);

    // ---- layer 1 ----
    k_gemm64<<<1024, 256, 0, stream>>>(x, W1, nullptr, 0, dinv, bufA, N);
    k_agg_buk<<<nbuk, 512, 0, stream>>>(bufA, dinv, bbase, epk, bufB, N);

    // ---- layer 2 ----
    k_gemm64<<<1024, 256, 0, stream>>>(bufB, W2, b1, 1, dinv, bufA, N);
    k_agg_buk<<<nbuk, 512, 0, stream>>>(bufA, dinv, bbase, epk, bufB, N);

    // ---- head: mean(relu(h2+b2)) @ Wfc + bfc ----
    hipMemsetAsync(csum, 0, 64 * sizeof(float), stream);
    k_colsum<<<1024, 256, 0, stream>>>(bufB, b2, csum, N);
    k_final<<<1, 64, 0, stream>>>(csum, Wfc, bfc, out, 1.0f / (float)N);
}

// Round 5
// 355.311 us; speedup vs baseline: 4.9784x; 4.9784x over previous
//
#include <hip/hip_runtime.h>

// ---------------------------------------------------------------------------
// GCN via bucket-built, node-sorted CSR. All per-edge atomics are LDS-only.
//   hs = dinv[row] * f(in) @ W         (GEMM, row-scale fused; f=relu(+bias) opt)
//   agg_i = dinv_i * ( hs_i + sum_{src->i} hs_src )
//   h1 = Agg(x@W1); h2 = Agg(relu(h1+b1)@W2); out = mean(relu(h2+b2))@Wfc+bfc
// Bucket = 128 consecutive dst nodes. Packed edge word: (dst&127)<<17 | src
// (needs N <= 2^17). edge_index arrives int32.
// ---------------------------------------------------------------------------

#define NSB 512  // scatter blocks

// per-(scatterblock, bucket) histogram; LDS atomics only
__global__ __launch_bounds__(256) void k_bcount(const int* __restrict__ dst,
                                                unsigned* __restrict__ cntBB,
                                                int E, int nbuk, int chunk) {
    __shared__ unsigned hist[1024];
    for (int i = threadIdx.x; i < nbuk; i += 256) hist[i] = 0u;
    __syncthreads();
    int lo = blockIdx.x * chunk, hi = min(E, lo + chunk);
    for (int e = lo + threadIdx.x; e < hi; e += 256)
        atomicAdd(&hist[((unsigned)dst[e]) >> 7], 1u);
    __syncthreads();
    for (int i = threadIdx.x; i < nbuk; i += 256)
        cntBB[(size_t)blockIdx.x * nbuk + i] = hist[i];
}

// per bucket k: exclusive scan of cntBB[t][k] over t (in place) + btot[k]=total
__global__ __launch_bounds__(NSB) void k_block_base(unsigned* __restrict__ cntBB,
                                                    unsigned* __restrict__ btot,
                                                    int nbuk) {
    __shared__ unsigned s[NSB];
    int k = blockIdx.x;
    int t = threadIdx.x;
    unsigned v = cntBB[(size_t)t * nbuk + k];
    s[t] = v;
    __syncthreads();
    for (int off = 1; off < NSB; off <<= 1) {
        unsigned a = (t >= off) ? s[t - off] : 0u;
        __syncthreads();
        s[t] += a;
        __syncthreads();
    }
    cntBB[(size_t)t * nbuk + k] = s[t] - v;       // local exclusive
    if (t == NSB - 1) btot[k] = s[NSB - 1];
}

// bbase = exclusive scan of btot (coalesced: one value per thread)
__global__ __launch_bounds__(1024) void k_scan_buckets(const unsigned* __restrict__ btot,
                                                       unsigned* __restrict__ bbase,
                                                       int nbuk) {
    __shared__ unsigned s[1024];
    int k = threadIdx.x;
    unsigned v = (k < nbuk) ? btot[k] : 0u;
    s[k] = v;
    __syncthreads();
    for (int off = 1; off < 1024; off <<= 1) {
        unsigned a = (k >= off) ? s[k - off] : 0u;
        __syncthreads();
        s[k] += a;
        __syncthreads();
    }
    if (k < nbuk) bbase[k] = s[k] - v;
    if (k == 0) bbase[nbuk] = s[1023];            // = E
}

// scatter packed edges into bucket segments; cursors in LDS
__global__ __launch_bounds__(256) void k_bscatter(const int* __restrict__ src,
                                                  const int* __restrict__ dst,
                                                  const unsigned* __restrict__ cntBB,
                                                  const unsigned* __restrict__ bbase,
                                                  unsigned* __restrict__ epk,
                                                  int E, int nbuk, int chunk) {
    __shared__ unsigned cur[1024];
    for (int i = threadIdx.x; i < nbuk; i += 256)
        cur[i] = bbase[i] + cntBB[(size_t)blockIdx.x * nbuk + i];
    __syncthreads();
    int lo = blockIdx.x * chunk, hi = min(E, lo + chunk);
    for (int e = lo + threadIdx.x; e < hi; e += 256) {
        unsigned d = (unsigned)dst[e];
        unsigned s = (unsigned)src[e];
        unsigned pos = atomicAdd(&cur[d >> 7], 1u);
        epk[pos] = ((d & 127u) << 17) | s;
    }
}

// per bucket: degree count + LDS scan -> rowptr/dinv; re-scatter to node-sorted esrc
__global__ __launch_bounds__(256) void k_sort(const unsigned* __restrict__ bbase,
                                              const unsigned* __restrict__ epk,
                                              int* __restrict__ esrc,
                                              unsigned* __restrict__ rowptr,
                                              float* __restrict__ dinv, int N, int E) {
    __shared__ unsigned cnt[128], scn[128];
    const int k = blockIdx.x;
    const int t = threadIdx.x;
    if (t < 128) cnt[t] = 0u;
    __syncthreads();
    const unsigned lo = bbase[k], hi = bbase[k + 1];
    for (unsigned e = lo + t; e < hi; e += 256)
        atomicAdd(&cnt[epk[e] >> 17], 1u);
    __syncthreads();
    unsigned c = (t < 128) ? cnt[t] : 0u;
    if (t < 128) scn[t] = c;
    __syncthreads();
    for (int off = 1; off < 128; off <<= 1) {
        unsigned a = (t < 128 && t >= off) ? scn[t - off] : 0u;
        __syncthreads();
        if (t < 128) scn[t] += a;
        __syncthreads();
    }
    int node = (k << 7) + t;
    if (t < 128) {
        unsigned start = scn[t] - c;
        cnt[t] = start;                            // becomes cursor
        if (node < N) {
            rowptr[node] = lo + start;
            dinv[node] = rsqrtf(1.0f + (float)c);
        }
    }
    if (k == gridDim.x - 1 && t == 0) rowptr[N] = (unsigned)E;
    __syncthreads();
    for (unsigned e = lo + t; e < hi; e += 256) {
        unsigned w = epk[e];
        unsigned pos = atomicAdd(&cnt[w >> 17], 1u);
        esrc[lo + pos] = (int)(w & 0x1FFFFu);
    }
}

// out[row][j] = rowscale[row] * sum_i f(in[row][i]) * W[i][j]; f=relu(v+bias) if relu_in
__global__ __launch_bounds__(256) void k_gemm64(const float* __restrict__ in,
                                                const float* __restrict__ W,
                                                const float* __restrict__ bias, int relu_in,
                                                const float* __restrict__ rowscale,
                                                float* __restrict__ out, int N) {
    __shared__ float Wl[64 * 64];
    for (int i = threadIdx.x; i < 64 * 64; i += 256) Wl[i] = W[i];
    __syncthreads();
    const int lane = threadIdx.x & 63;
    const int wave = threadIdx.x >> 6;
    const float bv = relu_in ? bias[lane] : 0.0f;
    for (int row = blockIdx.x * 4 + wave; row < N; row += gridDim.x * 4) {
        float x = in[(size_t)row * 64 + lane];
        if (relu_in) x = fmaxf(x + bv, 0.0f);
        float acc = 0.0f;
#pragma unroll
        for (int i = 0; i < 64; ++i)
            acc = fmaf(__shfl(x, i), Wl[i * 64 + lane], acc);
        out[(size_t)row * 64 + lane] = acc * rowscale[row];
    }
}

// node-parallel CSR gather: 16 threads/node, float4/thread, unroll 4
__global__ __launch_bounds__(256) void k_agg_csr(const float* __restrict__ hs,
                                                 const float* __restrict__ dinv,
                                                 const unsigned* __restrict__ rowptr,
                                                 const int* __restrict__ esrc,
                                                 float* __restrict__ out, int N) {
    int g = blockIdx.x * 16 + (threadIdx.x >> 4);
    if (g >= N) return;
    int c = (threadIdx.x & 15) * 4;
    unsigned k = rowptr[g], end = rowptr[g + 1];
    float4 sum = *reinterpret_cast<const float4*>(hs + (size_t)g * 64 + c);  // self-loop
    for (; k + 4 <= end; k += 4) {
        int s0 = esrc[k], s1 = esrc[k + 1], s2 = esrc[k + 2], s3 = esrc[k + 3];
        float4 a = *reinterpret_cast<const float4*>(hs + (size_t)s0 * 64 + c);
        float4 b = *reinterpret_cast<const float4*>(hs + (size_t)s1 * 64 + c);
        float4 d = *reinterpret_cast<const float4*>(hs + (size_t)s2 * 64 + c);
        float4 e = *reinterpret_cast<const float4*>(hs + (size_t)s3 * 64 + c);
        sum.x += (a.x + b.x) + (d.x + e.x);
        sum.y += (a.y + b.y) + (d.y + e.y);
        sum.z += (a.z + b.z) + (d.z + e.z);
        sum.w += (a.w + b.w) + (d.w + e.w);
    }
    for (; k < end; ++k) {
        int s = esrc[k];
        float4 a = *reinterpret_cast<const float4*>(hs + (size_t)s * 64 + c);
        sum.x += a.x; sum.y += a.y; sum.z += a.z; sum.w += a.w;
    }
    float di = dinv[g];
    float4 o;
    o.x = di * sum.x; o.y = di * sum.y; o.z = di * sum.z; o.w = di * sum.w;
    *reinterpret_cast<float4*>(out + (size_t)g * 64 + c) = o;
}

// colsum[j] = sum_rows relu(in[row][j] + bias[j])
__global__ __launch_bounds__(256) void k_colsum(const float* __restrict__ in,
                                                const float* __restrict__ bias,
                                                float* __restrict__ colsum, int N) {
    const int lane = threadIdx.x & 63;
    const int wave = threadIdx.x >> 6;
    const float bv = bias[lane];
    float acc = 0.0f;
    for (int row = blockIdx.x * 4 + wave; row < N; row += gridDim.x * 4)
        acc += fmaxf(in[(size_t)row * 64 + lane] + bv, 0.0f);
    __shared__ float red[4][64];
    red[wave][lane] = acc;
    __syncthreads();
    if (wave == 0)
        unsafeAtomicAdd(&colsum[lane],
                        red[0][lane] + red[1][lane] + red[2][lane] + red[3][lane]);
}

// out[j] = (colsum/N) @ Wfc + bfc
__global__ void k_final(const float* __restrict__ colsum, const float* __restrict__ Wfc,
                        const float* __restrict__ bfc, float* __restrict__ out, float invN) {
    int j = threadIdx.x;  // 64 threads
    float acc = 0.0f;
#pragma unroll
    for (int i = 0; i < 64; ++i)
        acc = fmaf(colsum[i] * invN, Wfc[i * 64 + j], acc);
    out[j] = acc + bfc[j];
}

extern "C" void kernel_launch(void* const* d_in, const int* in_sizes, int n_in,
                              void* d_out, int out_size, void* d_ws, size_t ws_size,
                              hipStream_t stream) {
    const float* x   = (const float*)d_in[0];
    const int*   ei  = (const int*)d_in[1];
    const float* W1  = (const float*)d_in[2];
    const float* b1  = (const float*)d_in[3];
    const float* W2  = (const float*)d_in[4];
    const float* b2  = (const float*)d_in[5];
    const float* Wfc = (const float*)d_in[6];
    const float* bfc = (const float*)d_in[7];
    float*       out = (float*)d_out;

    const int N = in_sizes[0] / 64;
    const int E = in_sizes[1] / 2;
    const int* src = ei;       // edge_index[0]
    const int* dst = ei + E;   // edge_index[1]

    const int nbuk  = (N + 127) >> 7;              // 782
    const int chunk = (E + NSB - 1) / NSB;

    char* ws = (char*)d_ws;
    const size_t NB = (size_t)N * 64 * sizeof(float);             // 25.6 MB
    const size_t N4 = (((size_t)(N + 1) * 4) + 255) & ~(size_t)255;
    const size_t E4 = (((size_t)E * 4) + 255) & ~(size_t)255;
    float*    bufA   = (float*)ws;
    float*    bufB   = (float*)(ws + NB);
    unsigned* cntBB  = (unsigned*)ws;              // aliases bufA (dead before GEMM1)
    unsigned* epk    = (unsigned*)(ws + NB);       // aliases bufB (dead before agg1)
    float*    dinv   = (float*)(ws + 2 * NB);
    unsigned* rowptr = (unsigned*)(ws + 2 * NB + N4);
    unsigned* bbase  = (unsigned*)(ws + 2 * NB + 2 * N4);
    unsigned* btot   = (unsigned*)(ws + 2 * NB + 2 * N4 + 4096);
    int*      esrc   = (int*)(ws + 2 * NB + 2 * N4 + 8192);
    float*    csum   = (float*)(ws + 2 * NB + 2 * N4 + 8192 + E4);

    // ---- bucket-CSR build (all per-edge atomics in LDS) ----
    k_bcount<<<NSB, 256, 0, stream>>>(dst, cntBB, E, nbuk, chunk);
    k_block_base<<<nbuk, NSB, 0, stream>>>(cntBB, btot, nbuk);
    k_scan_buckets<<<1, 1024, 0, stream>>>(btot, bbase, nbuk);
    k_bscatter<<<NSB, 256, 0, stream>>>(src, dst, cntBB, bbase, epk, E, nbuk, chunk);
    k_sort<<<nbuk, 256, 0, stream>>>(bbase, epk, esrc, rowptr, dinv, N, E);

    // ---- layer 1 ----
    k_gemm64<<<1024, 256, 0, stream>>>(x, W1, nullptr, 0, dinv, bufA, N);
    k_agg_csr<<<(N + 15) / 16, 256, 0, stream>>>(bufA, dinv, rowptr, esrc, bufB, N);

    // ---- layer 2 ----
    k_gemm64<<<1024, 256, 0, stream>>>(bufB, W2, b1, 1, dinv, bufA, N);
    k_agg_csr<<<(N + 15) / 16, 256, 0, stream>>>(bufA, dinv, rowptr, esrc, bufB, N);

    // ---- head: mean(relu(h2+b2)) @ Wfc + bfc ----
    hipMemsetAsync(csum, 0, 64 * sizeof(float), stream);
    k_colsum<<<1024, 256, 0, stream>>>(bufB, b2, csum, N);
    k_final<<<1, 64, 0, stream>>>(csum, Wfc, bfc, out, 1.0f / (float)N);
}

// Round 6
// 299.003 us; speedup vs baseline: 5.9159x; 1.1883x over previous
//
#include <hip/hip_runtime.h>

// ---------------------------------------------------------------------------
// GCN via bucket-built, node-sorted CSR. All per-edge atomics are LDS-only.
//   GEMM:  hs = dinv[row] * (in @ W)      (x in SGPRs via uniform row, W in VGPRs)
//   AGG:   out_i = relu( dinv_i*(hs_i + sum_{src->i} hs_src) + bias )
//   h1r = Agg(x@W1,b1); h2r = Agg(h1r@W2,b2); out = mean(h2r)@Wfc+bfc
// Bucket = 128 consecutive dst nodes. Packed edge word: (dst&127)<<17 | src
// (needs N <= 2^17). edge_index arrives int32.
// ---------------------------------------------------------------------------

#define NSB 512  // scatter blocks

// per-(scatterblock, bucket) histogram; LDS atomics only
__global__ __launch_bounds__(256) void k_bcount(const int* __restrict__ dst,
                                                unsigned* __restrict__ cntBB,
                                                int E, int nbuk, int chunk) {
    __shared__ unsigned hist[1024];
    for (int i = threadIdx.x; i < nbuk; i += 256) hist[i] = 0u;
    __syncthreads();
    int lo = blockIdx.x * chunk, hi = min(E, lo + chunk);
    for (int e = lo + threadIdx.x; e < hi; e += 256)
        atomicAdd(&hist[((unsigned)dst[e]) >> 7], 1u);
    __syncthreads();
    for (int i = threadIdx.x; i < nbuk; i += 256)
        cntBB[(size_t)blockIdx.x * nbuk + i] = hist[i];
}

// per bucket k: exclusive scan of cntBB[t][k] over t (in place) + btot[k]=total
__global__ __launch_bounds__(NSB) void k_block_base(unsigned* __restrict__ cntBB,
                                                    unsigned* __restrict__ btot,
                                                    int nbuk) {
    __shared__ unsigned s[NSB];
    int k = blockIdx.x;
    int t = threadIdx.x;
    unsigned v = cntBB[(size_t)t * nbuk + k];
    s[t] = v;
    __syncthreads();
    for (int off = 1; off < NSB; off <<= 1) {
        unsigned a = (t >= off) ? s[t - off] : 0u;
        __syncthreads();
        s[t] += a;
        __syncthreads();
    }
    cntBB[(size_t)t * nbuk + k] = s[t] - v;       // local exclusive
    if (t == NSB - 1) btot[k] = s[NSB - 1];
}

// bbase = exclusive scan of btot (coalesced: one value per thread)
__global__ __launch_bounds__(1024) void k_scan_buckets(const unsigned* __restrict__ btot,
                                                       unsigned* __restrict__ bbase,
                                                       int nbuk) {
    __shared__ unsigned s[1024];
    int k = threadIdx.x;
    unsigned v = (k < nbuk) ? btot[k] : 0u;
    s[k] = v;
    __syncthreads();
    for (int off = 1; off < 1024; off <<= 1) {
        unsigned a = (k >= off) ? s[k - off] : 0u;
        __syncthreads();
        s[k] += a;
        __syncthreads();
    }
    if (k < nbuk) bbase[k] = s[k] - v;
    if (k == 0) bbase[nbuk] = s[1023];            // = E
}

// scatter packed edges into bucket segments; cursors in LDS
__global__ __launch_bounds__(256) void k_bscatter(const int* __restrict__ src,
                                                  const int* __restrict__ dst,
                                                  const unsigned* __restrict__ cntBB,
                                                  const unsigned* __restrict__ bbase,
                                                  unsigned* __restrict__ epk,
                                                  int E, int nbuk, int chunk) {
    __shared__ unsigned cur[1024];
    for (int i = threadIdx.x; i < nbuk; i += 256)
        cur[i] = bbase[i] + cntBB[(size_t)blockIdx.x * nbuk + i];
    __syncthreads();
    int lo = blockIdx.x * chunk, hi = min(E, lo + chunk);
    for (int e = lo + threadIdx.x; e < hi; e += 256) {
        unsigned d = (unsigned)dst[e];
        unsigned s = (unsigned)src[e];
        unsigned pos = atomicAdd(&cur[d >> 7], 1u);
        epk[pos] = ((d & 127u) << 17) | s;
    }
}

// per bucket: degree count + LDS scan -> rowptr/dinv; re-scatter to node-sorted esrc
__global__ __launch_bounds__(256) void k_sort(const unsigned* __restrict__ bbase,
                                              const unsigned* __restrict__ epk,
                                              int* __restrict__ esrc,
                                              unsigned* __restrict__ rowptr,
                                              float* __restrict__ dinv, int N, int E) {
    __shared__ unsigned cnt[128], scn[128];
    const int k = blockIdx.x;
    const int t = threadIdx.x;
    if (t < 128) cnt[t] = 0u;
    __syncthreads();
    const unsigned lo = bbase[k], hi = bbase[k + 1];
    for (unsigned e = lo + t; e < hi; e += 256)
        atomicAdd(&cnt[epk[e] >> 17], 1u);
    __syncthreads();
    unsigned c = (t < 128) ? cnt[t] : 0u;
    if (t < 128) scn[t] = c;
    __syncthreads();
    for (int off = 1; off < 128; off <<= 1) {
        unsigned a = (t < 128 && t >= off) ? scn[t - off] : 0u;
        __syncthreads();
        if (t < 128) scn[t] += a;
        __syncthreads();
    }
    int node = (k << 7) + t;
    if (t < 128) {
        unsigned start = scn[t] - c;
        cnt[t] = start;                            // becomes cursor
        if (node < N) {
            rowptr[node] = lo + start;
            dinv[node] = rsqrtf(1.0f + (float)c);
        }
    }
    if (k == gridDim.x - 1 && t == 0) rowptr[N] = (unsigned)E;
    __syncthreads();
    for (unsigned e = lo + t; e < hi; e += 256) {
        unsigned w = epk[e];
        unsigned pos = atomicAdd(&cnt[w >> 17], 1u);
        esrc[lo + pos] = (int)(w & 0x1FFFFu);
    }
}

// out[row][lane] = rowscale[row] * sum_i in[row][i]*W[i][lane]
// row is wave-uniform -> x row scalarizes to s_load; W column lives in VGPRs.
__global__ __launch_bounds__(256) void k_gemm64s(const float* __restrict__ in,
                                                 const float* __restrict__ W,
                                                 const float* __restrict__ rowscale,
                                                 float* __restrict__ out, int N) {
    const int lane = threadIdx.x & 63;
    float w[64];
#pragma unroll
    for (int i = 0; i < 64; ++i) w[i] = W[i * 64 + lane];
    const int wv = __builtin_amdgcn_readfirstlane(threadIdx.x >> 6);  // uniform wave id
    const int stride = gridDim.x * 4;
    for (int row = blockIdx.x * 4 + wv; row < N; row += stride) {
        const float* __restrict__ xr = in + (size_t)row * 64;
        float acc = 0.0f;
#pragma unroll
        for (int i = 0; i < 64; ++i) acc = fmaf(xr[i], w[i], acc);
        out[(size_t)row * 64 + lane] = acc * rowscale[row];
    }
}

// node-parallel CSR gather: 16 threads/node, float4/thread, unroll 4.
// Epilogue: relu(dinv*sum + bias)  (bias/relu applied post-aggregation as in ref).
__global__ __launch_bounds__(256) void k_agg_csr(const float* __restrict__ hs,
                                                 const float* __restrict__ dinv,
                                                 const unsigned* __restrict__ rowptr,
                                                 const int* __restrict__ esrc,
                                                 const float* __restrict__ bias,
                                                 float* __restrict__ out, int N) {
    int g = blockIdx.x * 16 + (threadIdx.x >> 4);
    if (g >= N) return;
    int c = (threadIdx.x & 15) * 4;
    unsigned k = rowptr[g], end = rowptr[g + 1];
    float4 sum = *reinterpret_cast<const float4*>(hs + (size_t)g * 64 + c);  // self-loop
    for (; k + 4 <= end; k += 4) {
        int s0 = esrc[k], s1 = esrc[k + 1], s2 = esrc[k + 2], s3 = esrc[k + 3];
        float4 a = *reinterpret_cast<const float4*>(hs + (size_t)s0 * 64 + c);
        float4 b = *reinterpret_cast<const float4*>(hs + (size_t)s1 * 64 + c);
        float4 d = *reinterpret_cast<const float4*>(hs + (size_t)s2 * 64 + c);
        float4 e = *reinterpret_cast<const float4*>(hs + (size_t)s3 * 64 + c);
        sum.x += (a.x + b.x) + (d.x + e.x);
        sum.y += (a.y + b.y) + (d.y + e.y);
        sum.z += (a.z + b.z) + (d.z + e.z);
        sum.w += (a.w + b.w) + (d.w + e.w);
    }
    for (; k < end; ++k) {
        int s = esrc[k];
        float4 a = *reinterpret_cast<const float4*>(hs + (size_t)s * 64 + c);
        sum.x += a.x; sum.y += a.y; sum.z += a.z; sum.w += a.w;
    }
    float di = dinv[g];
    float4 bv = *reinterpret_cast<const float4*>(bias + c);
    float4 o;
    o.x = fmaxf(fmaf(di, sum.x, bv.x), 0.0f);
    o.y = fmaxf(fmaf(di, sum.y, bv.y), 0.0f);
    o.z = fmaxf(fmaf(di, sum.z, bv.z), 0.0f);
    o.w = fmaxf(fmaf(di, sum.w, bv.w), 0.0f);
    *reinterpret_cast<float4*>(out + (size_t)g * 64 + c) = o;
}

// colsum[j] = sum_rows in[row][j]   (input already rectified+biased)
__global__ __launch_bounds__(256) void k_colsum(const float* __restrict__ in,
                                                float* __restrict__ colsum, int N) {
    const int lane = threadIdx.x & 63;
    const int wave = threadIdx.x >> 6;
    float acc = 0.0f;
    for (int row = blockIdx.x * 4 + wave; row < N; row += gridDim.x * 4)
        acc += in[(size_t)row * 64 + lane];
    __shared__ float red[4][64];
    red[wave][lane] = acc;
    __syncthreads();
    if (wave == 0)
        unsafeAtomicAdd(&colsum[lane],
                        red[0][lane] + red[1][lane] + red[2][lane] + red[3][lane]);
}

// out[j] = (colsum/N) @ Wfc + bfc
__global__ void k_final(const float* __restrict__ colsum, const float* __restrict__ Wfc,
                        const float* __restrict__ bfc, float* __restrict__ out, float invN) {
    int j = threadIdx.x;  // 64 threads
    float acc = 0.0f;
#pragma unroll
    for (int i = 0; i < 64; ++i)
        acc = fmaf(colsum[i] * invN, Wfc[i * 64 + j], acc);
    out[j] = acc + bfc[j];
}

extern "C" void kernel_launch(void* const* d_in, const int* in_sizes, int n_in,
                              void* d_out, int out_size, void* d_ws, size_t ws_size,
                              hipStream_t stream) {
    const float* x   = (const float*)d_in[0];
    const int*   ei  = (const int*)d_in[1];
    const float* W1  = (const float*)d_in[2];
    const float* b1  = (const float*)d_in[3];
    const float* W2  = (const float*)d_in[4];
    const float* b2  = (const float*)d_in[5];
    const float* Wfc = (const float*)d_in[6];
    const float* bfc = (const float*)d_in[7];
    float*       out = (float*)d_out;

    const int N = in_sizes[0] / 64;
    const int E = in_sizes[1] / 2;
    const int* src = ei;       // edge_index[0]
    const int* dst = ei + E;   // edge_index[1]

    const int nbuk  = (N + 127) >> 7;              // 782
    const int chunk = (E + NSB - 1) / NSB;

    char* ws = (char*)d_ws;
    const size_t NB = (size_t)N * 64 * sizeof(float);             // 25.6 MB
    const size_t N4 = (((size_t)(N + 1) * 4) + 255) & ~(size_t)255;
    const size_t E4 = (((size_t)E * 4) + 255) & ~(size_t)255;
    float*    bufA   = (float*)ws;
    float*    bufB   = (float*)(ws + NB);
    unsigned* cntBB  = (unsigned*)ws;              // aliases bufA (dead before GEMM1)
    unsigned* epk    = (unsigned*)(ws + NB);       // aliases bufB (dead before agg1)
    float*    dinv   = (float*)(ws + 2 * NB);
    unsigned* rowptr = (unsigned*)(ws + 2 * NB + N4);
    unsigned* bbase  = (unsigned*)(ws + 2 * NB + 2 * N4);
    unsigned* btot   = (unsigned*)(ws + 2 * NB + 2 * N4 + 4096);
    int*      esrc   = (int*)(ws + 2 * NB + 2 * N4 + 8192);
    float*    csum   = (float*)(ws + 2 * NB + 2 * N4 + 8192 + E4);

    // ---- bucket-CSR build (all per-edge atomics in LDS) ----
    k_bcount<<<NSB, 256, 0, stream>>>(dst, cntBB, E, nbuk, chunk);
    k_block_base<<<nbuk, NSB, 0, stream>>>(cntBB, btot, nbuk);
    k_scan_buckets<<<1, 1024, 0, stream>>>(btot, bbase, nbuk);
    k_bscatter<<<NSB, 256, 0, stream>>>(src, dst, cntBB, bbase, epk, E, nbuk, chunk);
    k_sort<<<nbuk, 256, 0, stream>>>(bbase, epk, esrc, rowptr, dinv, N, E);

    // ---- layer 1 ----
    k_gemm64s<<<1024, 256, 0, stream>>>(x, W1, dinv, bufA, N);
    k_agg_csr<<<(N + 15) / 16, 256, 0, stream>>>(bufA, dinv, rowptr, esrc, b1, bufB, N);

    // ---- layer 2 ----
    k_gemm64s<<<1024, 256, 0, stream>>>(bufB, W2, dinv, bufA, N);
    k_agg_csr<<<(N + 15) / 16, 256, 0, stream>>>(bufA, dinv, rowptr, esrc, b2, bufB, N);

    // ---- head: mean(h2r) @ Wfc + bfc ----
    hipMemsetAsync(csum, 0, 64 * sizeof(float), stream);
    k_colsum<<<1024, 256, 0, stream>>>(bufB, csum, N);
    k_final<<<1, 64, 0, stream>>>(csum, Wfc, bfc, out, 1.0f / (float)N);
}

// Round 7
// 263.028 us; speedup vs baseline: 6.7250x; 1.1368x over previous
//
#include <hip/hip_runtime.h>

// ---------------------------------------------------------------------------
// GCN via bucket-built, node-sorted CSR. All per-edge atomics are LDS-only.
//   GEMM:  hs = dinv[row] * (in @ W)   (x rows in SGPRs via uniform addr,
//                                       W column in VGPRs, 4-row ILP)
//   AGG:   out_i = relu( dinv_i*(hs_i + sum_{src->i} hs_src) + bias )
//   h1r = Agg(x@W1,b1); h2r = Agg(h1r@W2,b2); out = mean(h2r)@Wfc+bfc
// Bucket = 128 consecutive dst nodes. Packed edge word: (dst&127)<<17 | src
// (needs N <= 2^17). edge_index arrives int32.
// ---------------------------------------------------------------------------

#define NSB 512  // scatter blocks

// per-(scatterblock, bucket) histogram; LDS atomics only
__global__ __launch_bounds__(256) void k_bcount(const int* __restrict__ dst,
                                                unsigned* __restrict__ cntBB,
                                                int E, int nbuk, int chunk) {
    __shared__ unsigned hist[1024];
    for (int i = threadIdx.x; i < nbuk; i += 256) hist[i] = 0u;
    __syncthreads();
    int lo = blockIdx.x * chunk, hi = min(E, lo + chunk);
    for (int e = lo + threadIdx.x; e < hi; e += 256)
        atomicAdd(&hist[((unsigned)dst[e]) >> 7], 1u);
    __syncthreads();
    for (int i = threadIdx.x; i < nbuk; i += 256)
        cntBB[(size_t)blockIdx.x * nbuk + i] = hist[i];
}

// per bucket k: exclusive scan of cntBB[t][k] over t (in place) + btot[k]=total
__global__ __launch_bounds__(NSB) void k_block_base(unsigned* __restrict__ cntBB,
                                                    unsigned* __restrict__ btot,
                                                    int nbuk) {
    __shared__ unsigned s[NSB];
    int k = blockIdx.x;
    int t = threadIdx.x;
    unsigned v = cntBB[(size_t)t * nbuk + k];
    s[t] = v;
    __syncthreads();
    for (int off = 1; off < NSB; off <<= 1) {
        unsigned a = (t >= off) ? s[t - off] : 0u;
        __syncthreads();
        s[t] += a;
        __syncthreads();
    }
    cntBB[(size_t)t * nbuk + k] = s[t] - v;       // local exclusive
    if (t == NSB - 1) btot[k] = s[NSB - 1];
}

// bbase = exclusive scan of btot (coalesced: one value per thread)
__global__ __launch_bounds__(1024) void k_scan_buckets(const unsigned* __restrict__ btot,
                                                       unsigned* __restrict__ bbase,
                                                       int nbuk) {
    __shared__ unsigned s[1024];
    int k = threadIdx.x;
    unsigned v = (k < nbuk) ? btot[k] : 0u;
    s[k] = v;
    __syncthreads();
    for (int off = 1; off < 1024; off <<= 1) {
        unsigned a = (k >= off) ? s[k - off] : 0u;
        __syncthreads();
        s[k] += a;
        __syncthreads();
    }
    if (k < nbuk) bbase[k] = s[k] - v;
    if (k == 0) bbase[nbuk] = s[1023];            // = E
}

// scatter packed edges into bucket segments; cursors in LDS
__global__ __launch_bounds__(256) void k_bscatter(const int* __restrict__ src,
                                                  const int* __restrict__ dst,
                                                  const unsigned* __restrict__ cntBB,
                                                  const unsigned* __restrict__ bbase,
                                                  unsigned* __restrict__ epk,
                                                  int E, int nbuk, int chunk) {
    __shared__ unsigned cur[1024];
    for (int i = threadIdx.x; i < nbuk; i += 256)
        cur[i] = bbase[i] + cntBB[(size_t)blockIdx.x * nbuk + i];
    __syncthreads();
    int lo = blockIdx.x * chunk, hi = min(E, lo + chunk);
    for (int e = lo + threadIdx.x; e < hi; e += 256) {
        unsigned d = (unsigned)dst[e];
        unsigned s = (unsigned)src[e];
        unsigned pos = atomicAdd(&cur[d >> 7], 1u);
        epk[pos] = ((d & 127u) << 17) | s;
    }
}

// per bucket: degree count + LDS scan -> rowptr/dinv; re-scatter to node-sorted esrc
__global__ __launch_bounds__(256) void k_sort(const unsigned* __restrict__ bbase,
                                              const unsigned* __restrict__ epk,
                                              int* __restrict__ esrc,
                                              unsigned* __restrict__ rowptr,
                                              float* __restrict__ dinv, int N, int E) {
    __shared__ unsigned cnt[128], scn[128];
    const int k = blockIdx.x;
    const int t = threadIdx.x;
    if (t < 128) cnt[t] = 0u;
    __syncthreads();
    const unsigned lo = bbase[k], hi = bbase[k + 1];
    for (unsigned e = lo + t; e < hi; e += 256)
        atomicAdd(&cnt[epk[e] >> 17], 1u);
    __syncthreads();
    unsigned c = (t < 128) ? cnt[t] : 0u;
    if (t < 128) scn[t] = c;
    __syncthreads();
    for (int off = 1; off < 128; off <<= 1) {
        unsigned a = (t < 128 && t >= off) ? scn[t - off] : 0u;
        __syncthreads();
        if (t < 128) scn[t] += a;
        __syncthreads();
    }
    int node = (k << 7) + t;
    if (t < 128) {
        unsigned start = scn[t] - c;
        cnt[t] = start;                            // becomes cursor
        if (node < N) {
            rowptr[node] = lo + start;
            dinv[node] = rsqrtf(1.0f + (float)c);
        }
    }
    if (k == gridDim.x - 1 && t == 0) rowptr[N] = (unsigned)E;
    __syncthreads();
    for (unsigned e = lo + t; e < hi; e += 256) {
        unsigned w = epk[e];
        unsigned pos = atomicAdd(&cnt[w >> 17], 1u);
        esrc[lo + pos] = (int)(w & 0x1FFFFu);
    }
}

// out[row][lane] = rowscale[row] * sum_i in[row][i]*W[i][lane]
// Wave-uniform row addresses -> x rows scalarize to s_load; W column in VGPRs.
// 4 rows per wave-iteration: 4 independent FMA chains (hide VALU latency).
__global__ __launch_bounds__(256) void k_gemm64s(const float* __restrict__ in,
                                                 const float* __restrict__ W,
                                                 const float* __restrict__ rowscale,
                                                 float* __restrict__ out, int N) {
    const int lane = threadIdx.x & 63;
    float w[64];
#pragma unroll
    for (int i = 0; i < 64; ++i) w[i] = W[i * 64 + lane];
    const int wv = __builtin_amdgcn_readfirstlane(threadIdx.x >> 6);  // uniform
    const int stride = gridDim.x * 16;
    for (int r0 = blockIdx.x * 16 + wv * 4; r0 < N; r0 += stride) {
        if (r0 + 4 <= N) {
            const float* __restrict__ x0 = in + (size_t)r0 * 64;
            float a0 = 0.f, a1 = 0.f, a2 = 0.f, a3 = 0.f;
#pragma unroll
            for (int i = 0; i < 64; ++i) {
                a0 = fmaf(x0[i],       w[i], a0);
                a1 = fmaf(x0[64 + i],  w[i], a1);
                a2 = fmaf(x0[128 + i], w[i], a2);
                a3 = fmaf(x0[192 + i], w[i], a3);
            }
            out[(size_t)r0 * 64 + lane]       = a0 * rowscale[r0];
            out[(size_t)(r0 + 1) * 64 + lane] = a1 * rowscale[r0 + 1];
            out[(size_t)(r0 + 2) * 64 + lane] = a2 * rowscale[r0 + 2];
            out[(size_t)(r0 + 3) * 64 + lane] = a3 * rowscale[r0 + 3];
        } else {
            for (int r = r0; r < N; ++r) {
                const float* __restrict__ xr = in + (size_t)r * 64;
                float a = 0.f;
#pragma unroll
                for (int i = 0; i < 64; ++i) a = fmaf(xr[i], w[i], a);
                out[(size_t)r * 64 + lane] = a * rowscale[r];
            }
        }
    }
}

// node-parallel CSR gather: 16 threads/node, float4/thread, unroll 4.
// Epilogue: relu(dinv*sum + bias)  (bias/relu applied post-aggregation as in ref).
__global__ __launch_bounds__(256) void k_agg_csr(const float* __restrict__ hs,
                                                 const float* __restrict__ dinv,
                                                 const unsigned* __restrict__ rowptr,
                                                 const int* __restrict__ esrc,
                                                 const float* __restrict__ bias,
                                                 float* __restrict__ out, int N) {
    int g = blockIdx.x * 16 + (threadIdx.x >> 4);
    if (g >= N) return;
    int c = (threadIdx.x & 15) * 4;
    unsigned k = rowptr[g], end = rowptr[g + 1];
    float4 sum = *reinterpret_cast<const float4*>(hs + (size_t)g * 64 + c);  // self-loop
    for (; k + 4 <= end; k += 4) {
        int s0 = esrc[k], s1 = esrc[k + 1], s2 = esrc[k + 2], s3 = esrc[k + 3];
        float4 a = *reinterpret_cast<const float4*>(hs + (size_t)s0 * 64 + c);
        float4 b = *reinterpret_cast<const float4*>(hs + (size_t)s1 * 64 + c);
        float4 d = *reinterpret_cast<const float4*>(hs + (size_t)s2 * 64 + c);
        float4 e = *reinterpret_cast<const float4*>(hs + (size_t)s3 * 64 + c);
        sum.x += (a.x + b.x) + (d.x + e.x);
        sum.y += (a.y + b.y) + (d.y + e.y);
        sum.z += (a.z + b.z) + (d.z + e.z);
        sum.w += (a.w + b.w) + (d.w + e.w);
    }
    for (; k < end; ++k) {
        int s = esrc[k];
        float4 a = *reinterpret_cast<const float4*>(hs + (size_t)s * 64 + c);
        sum.x += a.x; sum.y += a.y; sum.z += a.z; sum.w += a.w;
    }
    float di = dinv[g];
    float4 bv = *reinterpret_cast<const float4*>(bias + c);
    float4 o;
    o.x = fmaxf(fmaf(di, sum.x, bv.x), 0.0f);
    o.y = fmaxf(fmaf(di, sum.y, bv.y), 0.0f);
    o.z = fmaxf(fmaf(di, sum.z, bv.z), 0.0f);
    o.w = fmaxf(fmaf(di, sum.w, bv.w), 0.0f);
    *reinterpret_cast<float4*>(out + (size_t)g * 64 + c) = o;
}

// colsum[j] = sum_rows in[row][j]   (input already rectified+biased)
__global__ __launch_bounds__(256) void k_colsum(const float* __restrict__ in,
                                                float* __restrict__ colsum, int N) {
    const int lane = threadIdx.x & 63;
    const int wave = threadIdx.x >> 6;
    float acc = 0.0f;
    for (int row = blockIdx.x * 4 + wave; row < N; row += gridDim.x * 4)
        acc += in[(size_t)row * 64 + lane];
    __shared__ float red[4][64];
    red[wave][lane] = acc;
    __syncthreads();
    if (wave == 0)
        unsafeAtomicAdd(&colsum[lane],
                        red[0][lane] + red[1][lane] + red[2][lane] + red[3][lane]);
}

// out[j] = (colsum/N) @ Wfc + bfc
__global__ void k_final(const float* __restrict__ colsum, const float* __restrict__ Wfc,
                        const float* __restrict__ bfc, float* __restrict__ out, float invN) {
    int j = threadIdx.x;  // 64 threads
    float acc = 0.0f;
#pragma unroll
    for (int i = 0; i < 64; ++i)
        acc = fmaf(colsum[i] * invN, Wfc[i * 64 + j], acc);
    out[j] = acc + bfc[j];
}

extern "C" void kernel_launch(void* const* d_in, const int* in_sizes, int n_in,
                              void* d_out, int out_size, void* d_ws, size_t ws_size,
                              hipStream_t stream) {
    const float* x   = (const float*)d_in[0];
    const int*   ei  = (const int*)d_in[1];
    const float* W1  = (const float*)d_in[2];
    const float* b1  = (const float*)d_in[3];
    const float* W2  = (const float*)d_in[4];
    const float* b2  = (const float*)d_in[5];
    const float* Wfc = (const float*)d_in[6];
    const float* bfc = (const float*)d_in[7];
    float*       out = (float*)d_out;

    const int N = in_sizes[0] / 64;
    const int E = in_sizes[1] / 2;
    const int* src = ei;       // edge_index[0]
    const int* dst = ei + E;   // edge_index[1]

    const int nbuk  = (N + 127) >> 7;              // 782
    const int chunk = (E + NSB - 1) / NSB;

    char* ws = (char*)d_ws;
    const size_t NB = (size_t)N * 64 * sizeof(float);             // 25.6 MB
    const size_t N4 = (((size_t)(N + 1) * 4) + 255) & ~(size_t)255;
    const size_t E4 = (((size_t)E * 4) + 255) & ~(size_t)255;
    float*    bufA   = (float*)ws;
    float*    bufB   = (float*)(ws + NB);
    unsigned* cntBB  = (unsigned*)ws;              // aliases bufA (dead before GEMM1)
    unsigned* epk    = (unsigned*)(ws + NB);       // aliases bufB (dead before agg1)
    float*    dinv   = (float*)(ws + 2 * NB);
    unsigned* rowptr = (unsigned*)(ws + 2 * NB + N4);
    unsigned* bbase  = (unsigned*)(ws + 2 * NB + 2 * N4);
    unsigned* btot   = (unsigned*)(ws + 2 * NB + 2 * N4 + 4096);
    int*      esrc   = (int*)(ws + 2 * NB + 2 * N4 + 8192);
    float*    csum   = (float*)(ws + 2 * NB + 2 * N4 + 8192 + E4);

    // ---- bucket-CSR build (all per-edge atomics in LDS) ----
    k_bcount<<<NSB, 256, 0, stream>>>(dst, cntBB, E, nbuk, chunk);
    k_block_base<<<nbuk, NSB, 0, stream>>>(cntBB, btot, nbuk);
    k_scan_buckets<<<1, 1024, 0, stream>>>(btot, bbase, nbuk);
    k_bscatter<<<NSB, 256, 0, stream>>>(src, dst, cntBB, bbase, epk, E, nbuk, chunk);
    k_sort<<<nbuk, 256, 0, stream>>>(bbase, epk, esrc, rowptr, dinv, N, E);

    // ---- layer 1 ----
    k_gemm64s<<<1024, 256, 0, stream>>>(x, W1, dinv, bufA, N);
    k_agg_csr<<<(N + 15) / 16, 256, 0, stream>>>(bufA, dinv, rowptr, esrc, b1, bufB, N);

    // ---- layer 2 ----
    k_gemm64s<<<1024, 256, 0, stream>>>(bufB, W2, dinv, bufA, N);
    k_agg_csr<<<(N + 15) / 16, 256, 0, stream>>>(bufA, dinv, rowptr, esrc, b2, bufB, N);

    // ---- head: mean(h2r) @ Wfc + bfc ----
    hipMemsetAsync(csum, 0, 64 * sizeof(float), stream);
    k_colsum<<<1024, 256, 0, stream>>>(bufB, csum, N);
    k_final<<<1, 64, 0, stream>>>(csum, Wfc, bfc, out, 1.0f / (float)N);
}

// Round 8
// 217.635 us; speedup vs baseline: 8.1277x; 1.2086x over previous
//
#include <hip/hip_runtime.h>
#include <hip/hip_bf16.h>

// ---------------------------------------------------------------------------
// GCN via bucket-built, node-sorted CSR. All per-edge atomics are LDS-only.
//   GEMM:  hs = bf16( dinv[row] * (in @ W) )   (x rows via scalarized s_load,
//                                              W column in VGPRs, 4-row ILP)
//   AGG:   out_i = relu( dinv_i*(hs_i + sum_{src->i} hs_src) + bias )  [f32 acc]
//   h1r = Agg(x@W1,b1); h2r = Agg(h1r@W2,b2); out = mean(h2r)@Wfc+bfc
// Bucket = 128 consecutive dst nodes. Packed edge word: (dst&127)<<17 | src
// (needs N <= 2^17). edge_index arrives int32.
// ---------------------------------------------------------------------------

#define NSB 512  // scatter blocks

__device__ __forceinline__ float b2f(unsigned short u) {
    return __uint_as_float(((unsigned)u) << 16);
}

// per-(scatterblock, bucket) histogram; LDS atomics only
__global__ __launch_bounds__(256) void k_bcount(const int* __restrict__ dst,
                                                unsigned* __restrict__ cntBB,
                                                int E, int nbuk, int chunk) {
    __shared__ unsigned hist[1024];
    for (int i = threadIdx.x; i < nbuk; i += 256) hist[i] = 0u;
    __syncthreads();
    int lo = blockIdx.x * chunk, hi = min(E, lo + chunk);
    for (int e = lo + threadIdx.x; e < hi; e += 256)
        atomicAdd(&hist[((unsigned)dst[e]) >> 7], 1u);
    __syncthreads();
    for (int i = threadIdx.x; i < nbuk; i += 256)
        cntBB[(size_t)blockIdx.x * nbuk + i] = hist[i];
}

// per bucket k: exclusive scan of cntBB[t][k] over t (in place) + btot[k]=total
__global__ __launch_bounds__(NSB) void k_block_base(unsigned* __restrict__ cntBB,
                                                    unsigned* __restrict__ btot,
                                                    int nbuk) {
    __shared__ unsigned s[NSB];
    int k = blockIdx.x;
    int t = threadIdx.x;
    unsigned v = cntBB[(size_t)t * nbuk + k];
    s[t] = v;
    __syncthreads();
    for (int off = 1; off < NSB; off <<= 1) {
        unsigned a = (t >= off) ? s[t - off] : 0u;
        __syncthreads();
        s[t] += a;
        __syncthreads();
    }
    cntBB[(size_t)t * nbuk + k] = s[t] - v;       // local exclusive
    if (t == NSB - 1) btot[k] = s[NSB - 1];
}

// bbase = exclusive scan of btot (coalesced: one value per thread)
__global__ __launch_bounds__(1024) void k_scan_buckets(const unsigned* __restrict__ btot,
                                                       unsigned* __restrict__ bbase,
                                                       int nbuk) {
    __shared__ unsigned s[1024];
    int k = threadIdx.x;
    unsigned v = (k < nbuk) ? btot[k] : 0u;
    s[k] = v;
    __syncthreads();
    for (int off = 1; off < 1024; off <<= 1) {
        unsigned a = (k >= off) ? s[k - off] : 0u;
        __syncthreads();
        s[k] += a;
        __syncthreads();
    }
    if (k < nbuk) bbase[k] = s[k] - v;
    if (k == 0) bbase[nbuk] = s[1023];            // = E
}

// scatter packed edges into bucket segments; cursors in LDS
__global__ __launch_bounds__(256) void k_bscatter(const int* __restrict__ src,
                                                  const int* __restrict__ dst,
                                                  const unsigned* __restrict__ cntBB,
                                                  const unsigned* __restrict__ bbase,
                                                  unsigned* __restrict__ epk,
                                                  int E, int nbuk, int chunk) {
    __shared__ unsigned cur[1024];
    for (int i = threadIdx.x; i < nbuk; i += 256)
        cur[i] = bbase[i] + cntBB[(size_t)blockIdx.x * nbuk + i];
    __syncthreads();
    int lo = blockIdx.x * chunk, hi = min(E, lo + chunk);
    for (int e = lo + threadIdx.x; e < hi; e += 256) {
        unsigned d = (unsigned)dst[e];
        unsigned s = (unsigned)src[e];
        unsigned pos = atomicAdd(&cur[d >> 7], 1u);
        epk[pos] = ((d & 127u) << 17) | s;
    }
}

// per bucket: degree count + LDS scan -> rowptr/dinv; re-scatter to node-sorted esrc
__global__ __launch_bounds__(256) void k_sort(const unsigned* __restrict__ bbase,
                                              const unsigned* __restrict__ epk,
                                              int* __restrict__ esrc,
                                              unsigned* __restrict__ rowptr,
                                              float* __restrict__ dinv, int N, int E) {
    __shared__ unsigned cnt[128], scn[128];
    const int k = blockIdx.x;
    const int t = threadIdx.x;
    if (t < 128) cnt[t] = 0u;
    __syncthreads();
    const unsigned lo = bbase[k], hi = bbase[k + 1];
    for (unsigned e = lo + t; e < hi; e += 256)
        atomicAdd(&cnt[epk[e] >> 17], 1u);
    __syncthreads();
    unsigned c = (t < 128) ? cnt[t] : 0u;
    if (t < 128) scn[t] = c;
    __syncthreads();
    for (int off = 1; off < 128; off <<= 1) {
        unsigned a = (t < 128 && t >= off) ? scn[t - off] : 0u;
        __syncthreads();
        if (t < 128) scn[t] += a;
        __syncthreads();
    }
    int node = (k << 7) + t;
    if (t < 128) {
        unsigned start = scn[t] - c;
        cnt[t] = start;                            // becomes cursor
        if (node < N) {
            rowptr[node] = lo + start;
            dinv[node] = rsqrtf(1.0f + (float)c);
        }
    }
    if (k == gridDim.x - 1 && t == 0) rowptr[N] = (unsigned)E;
    __syncthreads();
    for (unsigned e = lo + t; e < hi; e += 256) {
        unsigned w = epk[e];
        unsigned pos = atomicAdd(&cnt[w >> 17], 1u);
        esrc[lo + pos] = (int)(w & 0x1FFFFu);
    }
}

// outb[row][lane] = bf16( rowscale[row] * sum_i in[row][i]*W[i][lane] )
// Wave-uniform row addresses -> x rows scalarize to s_load; W column in VGPRs.
// 4 rows per wave-iteration: 4 independent FMA chains.
__global__ __launch_bounds__(256) void k_gemm64s(const float* __restrict__ in,
                                                 const float* __restrict__ W,
                                                 const float* __restrict__ rowscale,
                                                 __hip_bfloat16* __restrict__ outb, int N) {
    const int lane = threadIdx.x & 63;
    float w[64];
#pragma unroll
    for (int i = 0; i < 64; ++i) w[i] = W[i * 64 + lane];
    const int wv = __builtin_amdgcn_readfirstlane(threadIdx.x >> 6);  // uniform
    const int stride = gridDim.x * 16;
    for (int r0 = blockIdx.x * 16 + wv * 4; r0 < N; r0 += stride) {
        if (r0 + 4 <= N) {
            const float* __restrict__ x0 = in + (size_t)r0 * 64;
            float a0 = 0.f, a1 = 0.f, a2 = 0.f, a3 = 0.f;
#pragma unroll
            for (int i = 0; i < 64; ++i) {
                a0 = fmaf(x0[i],       w[i], a0);
                a1 = fmaf(x0[64 + i],  w[i], a1);
                a2 = fmaf(x0[128 + i], w[i], a2);
                a3 = fmaf(x0[192 + i], w[i], a3);
            }
            outb[(size_t)r0 * 64 + lane]       = __float2bfloat16(a0 * rowscale[r0]);
            outb[(size_t)(r0 + 1) * 64 + lane] = __float2bfloat16(a1 * rowscale[r0 + 1]);
            outb[(size_t)(r0 + 2) * 64 + lane] = __float2bfloat16(a2 * rowscale[r0 + 2]);
            outb[(size_t)(r0 + 3) * 64 + lane] = __float2bfloat16(a3 * rowscale[r0 + 3]);
        } else {
            for (int r = r0; r < N; ++r) {
                const float* __restrict__ xr = in + (size_t)r * 64;
                float a = 0.f;
#pragma unroll
                for (int i = 0; i < 64; ++i) a = fmaf(xr[i], w[i], a);
                outb[(size_t)r * 64 + lane] = __float2bfloat16(a * rowscale[r]);
            }
        }
    }
}

// node-parallel CSR gather on bf16 hs: 16 threads/node, ushort4/thread, unroll 4.
// f32 accumulate; epilogue relu(dinv*sum + bias) written f32.
__global__ __launch_bounds__(256) void k_agg_csr(const __hip_bfloat16* __restrict__ hs,
                                                 const float* __restrict__ dinv,
                                                 const unsigned* __restrict__ rowptr,
                                                 const int* __restrict__ esrc,
                                                 const float* __restrict__ bias,
                                                 float* __restrict__ out, int N) {
    int g = blockIdx.x * 16 + (threadIdx.x >> 4);
    if (g >= N) return;
    int c = (threadIdx.x & 15) * 4;
    const ushort* hb = reinterpret_cast<const ushort*>(hs);
    unsigned k = rowptr[g], end = rowptr[g + 1];
    ushort4 sv = *reinterpret_cast<const ushort4*>(hb + (size_t)g * 64 + c);  // self
    float sx = b2f(sv.x), sy = b2f(sv.y), sz = b2f(sv.z), sw = b2f(sv.w);
    for (; k + 4 <= end; k += 4) {
        int s0 = esrc[k], s1 = esrc[k + 1], s2 = esrc[k + 2], s3 = esrc[k + 3];
        ushort4 a = *reinterpret_cast<const ushort4*>(hb + (size_t)s0 * 64 + c);
        ushort4 b = *reinterpret_cast<const ushort4*>(hb + (size_t)s1 * 64 + c);
        ushort4 d = *reinterpret_cast<const ushort4*>(hb + (size_t)s2 * 64 + c);
        ushort4 e = *reinterpret_cast<const ushort4*>(hb + (size_t)s3 * 64 + c);
        sx += (b2f(a.x) + b2f(b.x)) + (b2f(d.x) + b2f(e.x));
        sy += (b2f(a.y) + b2f(b.y)) + (b2f(d.y) + b2f(e.y));
        sz += (b2f(a.z) + b2f(b.z)) + (b2f(d.z) + b2f(e.z));
        sw += (b2f(a.w) + b2f(b.w)) + (b2f(d.w) + b2f(e.w));
    }
    for (; k < end; ++k) {
        int s = esrc[k];
        ushort4 a = *reinterpret_cast<const ushort4*>(hb + (size_t)s * 64 + c);
        sx += b2f(a.x); sy += b2f(a.y); sz += b2f(a.z); sw += b2f(a.w);
    }
    float di = dinv[g];
    float4 bv = *reinterpret_cast<const float4*>(bias + c);
    float4 o;
    o.x = fmaxf(fmaf(di, sx, bv.x), 0.0f);
    o.y = fmaxf(fmaf(di, sy, bv.y), 0.0f);
    o.z = fmaxf(fmaf(di, sz, bv.z), 0.0f);
    o.w = fmaxf(fmaf(di, sw, bv.w), 0.0f);
    *reinterpret_cast<float4*>(out + (size_t)g * 64 + c) = o;
}

// colsum[j] = sum_rows in[row][j]   (input already rectified+biased)
__global__ __launch_bounds__(256) void k_colsum(const float* __restrict__ in,
                                                float* __restrict__ colsum, int N) {
    const int lane = threadIdx.x & 63;
    const int wave = threadIdx.x >> 6;
    float acc = 0.0f;
    for (int row = blockIdx.x * 4 + wave; row < N; row += gridDim.x * 4)
        acc += in[(size_t)row * 64 + lane];
    __shared__ float red[4][64];
    red[wave][lane] = acc;
    __syncthreads();
    if (wave == 0)
        unsafeAtomicAdd(&colsum[lane],
                        red[0][lane] + red[1][lane] + red[2][lane] + red[3][lane]);
}

// out[j] = (colsum/N) @ Wfc + bfc
__global__ void k_final(const float* __restrict__ colsum, const float* __restrict__ Wfc,
                        const float* __restrict__ bfc, float* __restrict__ out, float invN) {
    int j = threadIdx.x;  // 64 threads
    float acc = 0.0f;
#pragma unroll
    for (int i = 0; i < 64; ++i)
        acc = fmaf(colsum[i] * invN, Wfc[i * 64 + j], acc);
    out[j] = acc + bfc[j];
}

extern "C" void kernel_launch(void* const* d_in, const int* in_sizes, int n_in,
                              void* d_out, int out_size, void* d_ws, size_t ws_size,
                              hipStream_t stream) {
    const float* x   = (const float*)d_in[0];
    const int*   ei  = (const int*)d_in[1];
    const float* W1  = (const float*)d_in[2];
    const float* b1  = (const float*)d_in[3];
    const float* W2  = (const float*)d_in[4];
    const float* b2  = (const float*)d_in[5];
    const float* Wfc = (const float*)d_in[6];
    const float* bfc = (const float*)d_in[7];
    float*       out = (float*)d_out;

    const int N = in_sizes[0] / 64;
    const int E = in_sizes[1] / 2;
    const int* src = ei;       // edge_index[0]
    const int* dst = ei + E;   // edge_index[1]

    const int nbuk  = (N + 127) >> 7;              // 782
    const int chunk = (E + NSB - 1) / NSB;

    char* ws = (char*)d_ws;
    const size_t NB2 = (size_t)N * 64 * sizeof(__hip_bfloat16);   // 12.8 MB (hs)
    const size_t NB4 = (size_t)N * 64 * sizeof(float);            // 25.6 MB
    const size_t N4  = (((size_t)(N + 1) * 4) + 255) & ~(size_t)255;
    const size_t E4  = (((size_t)E * 4) + 255) & ~(size_t)255;
    __hip_bfloat16* bufA = (__hip_bfloat16*)ws;                   // hs (bf16)
    float*    bufB   = (float*)(ws + NB2);                        // agg out (f32)
    unsigned* cntBB  = (unsigned*)ws;              // aliases bufA (dead before GEMM1)
    unsigned* epk    = (unsigned*)(ws + NB2);      // aliases bufB (dead before agg1)
    float*    dinv   = (float*)(ws + NB2 + NB4);
    unsigned* rowptr = (unsigned*)(ws + NB2 + NB4 + N4);
    unsigned* bbase  = (unsigned*)(ws + NB2 + NB4 + 2 * N4);
    unsigned* btot   = (unsigned*)(ws + NB2 + NB4 + 2 * N4 + 4096);
    int*      esrc   = (int*)(ws + NB2 + NB4 + 2 * N4 + 8192);
    float*    csum   = (float*)(ws + NB2 + NB4 + 2 * N4 + 8192 + E4);

    // ---- bucket-CSR build (all per-edge atomics in LDS) ----
    k_bcount<<<NSB, 256, 0, stream>>>(dst, cntBB, E, nbuk, chunk);
    k_block_base<<<nbuk, NSB, 0, stream>>>(cntBB, btot, nbuk);
    k_scan_buckets<<<1, 1024, 0, stream>>>(btot, bbase, nbuk);
    k_bscatter<<<NSB, 256, 0, stream>>>(src, dst, cntBB, bbase, epk, E, nbuk, chunk);
    k_sort<<<nbuk, 256, 0, stream>>>(bbase, epk, esrc, rowptr, dinv, N, E);

    // ---- layer 1 ----
    k_gemm64s<<<1024, 256, 0, stream>>>(x, W1, dinv, bufA, N);
    k_agg_csr<<<(N + 15) / 16, 256, 0, stream>>>(bufA, dinv, rowptr, esrc, b1, bufB, N);

    // ---- layer 2 ----
    k_gemm64s<<<1024, 256, 0, stream>>>(bufB, W2, dinv, bufA, N);
    k_agg_csr<<<(N + 15) / 16, 256, 0, stream>>>(bufA, dinv, rowptr, esrc, b2, bufB, N);

    // ---- head: mean(h2r) @ Wfc + bfc ----
    hipMemsetAsync(csum, 0, 64 * sizeof(float), stream);
    k_colsum<<<1024, 256, 0, stream>>>(bufB, csum, N);
    k_final<<<1, 64, 0, stream>>>(csum, Wfc, bfc, out, 1.0f / (float)N);
}

// Round 9
// 191.733 us; speedup vs baseline: 9.2257x; 1.1351x over previous
//
#include <hip/hip_runtime.h>
#include <hip/hip_bf16.h>

// ---------------------------------------------------------------------------
// GCN via bucket-built, node-sorted CSR + MFMA GEMM.
//   GEMM:  hs = bf16( dinv[row] * (in @ W) )  via mfma_f32_16x16x32_bf16,
//          W split W=Whi+Wlo (bf16 pair) -> f32-accurate weights.
//   AGG:   out_i = relu( dinv_i*(hs_i + sum_{src->i} hs_src) + bias ) [f32 acc]
//   h1r = Agg(x@W1,b1); h2r = Agg(h1r@W2,b2); out = mean(h2r)@Wfc+bfc
// Bucket = 128 consecutive dst nodes; packed edge word (dst&127)<<17|src.
// edge_index arrives int32. All per-edge atomics are LDS-only.
// ---------------------------------------------------------------------------

#define NSB 512  // scatter blocks

typedef __attribute__((ext_vector_type(8))) short short8v;
typedef __attribute__((ext_vector_type(4))) float float4v;

__device__ __forceinline__ float b2f(unsigned short u) {
    return __uint_as_float(((unsigned)u) << 16);
}
__device__ __forceinline__ unsigned short f2b(float f) {  // RNE f32->bf16
    unsigned u = __float_as_uint(f);
    return (unsigned short)((u + 0x7fffu + ((u >> 16) & 1u)) >> 16);
}

// per-(scatterblock, bucket) histogram; LDS atomics only
__global__ __launch_bounds__(256) void k_bcount(const int* __restrict__ dst,
                                                unsigned* __restrict__ cntBB,
                                                int E, int nbuk, int chunk) {
    __shared__ unsigned hist[1024];
    for (int i = threadIdx.x; i < nbuk; i += 256) hist[i] = 0u;
    __syncthreads();
    int lo = blockIdx.x * chunk, hi = min(E, lo + chunk);
    for (int e = lo + threadIdx.x; e < hi; e += 256)
        atomicAdd(&hist[((unsigned)dst[e]) >> 7], 1u);
    __syncthreads();
    for (int i = threadIdx.x; i < nbuk; i += 256)
        cntBB[(size_t)blockIdx.x * nbuk + i] = hist[i];
}

// per bucket k: exclusive scan of cntBB[t][k] over t (in place) + btot[k]=total
__global__ __launch_bounds__(NSB) void k_block_base(unsigned* __restrict__ cntBB,
                                                    unsigned* __restrict__ btot,
                                                    int nbuk) {
    __shared__ unsigned s[NSB];
    int k = blockIdx.x;
    int t = threadIdx.x;
    unsigned v = cntBB[(size_t)t * nbuk + k];
    s[t] = v;
    __syncthreads();
    for (int off = 1; off < NSB; off <<= 1) {
        unsigned a = (t >= off) ? s[t - off] : 0u;
        __syncthreads();
        s[t] += a;
        __syncthreads();
    }
    cntBB[(size_t)t * nbuk + k] = s[t] - v;       // local exclusive
    if (t == NSB - 1) btot[k] = s[NSB - 1];
}

// bbase = exclusive scan of btot; also zero csum (used much later by colsum)
__global__ __launch_bounds__(1024) void k_scan_buckets(const unsigned* __restrict__ btot,
                                                       unsigned* __restrict__ bbase,
                                                       float* __restrict__ csum,
                                                       int nbuk) {
    __shared__ unsigned s[1024];
    int k = threadIdx.x;
    if (k < 64) csum[k] = 0.0f;
    unsigned v = (k < nbuk) ? btot[k] : 0u;
    s[k] = v;
    __syncthreads();
    for (int off = 1; off < 1024; off <<= 1) {
        unsigned a = (k >= off) ? s[k - off] : 0u;
        __syncthreads();
        s[k] += a;
        __syncthreads();
    }
    if (k < nbuk) bbase[k] = s[k] - v;
    if (k == 0) bbase[nbuk] = s[1023];            // = E
}

// scatter packed edges into bucket segments; cursors in LDS
__global__ __launch_bounds__(256) void k_bscatter(const int* __restrict__ src,
                                                  const int* __restrict__ dst,
                                                  const unsigned* __restrict__ cntBB,
                                                  const unsigned* __restrict__ bbase,
                                                  unsigned* __restrict__ epk,
                                                  int E, int nbuk, int chunk) {
    __shared__ unsigned cur[1024];
    for (int i = threadIdx.x; i < nbuk; i += 256)
        cur[i] = bbase[i] + cntBB[(size_t)blockIdx.x * nbuk + i];
    __syncthreads();
    int lo = blockIdx.x * chunk, hi = min(E, lo + chunk);
    for (int e = lo + threadIdx.x; e < hi; e += 256) {
        unsigned d = (unsigned)dst[e];
        unsigned s = (unsigned)src[e];
        unsigned pos = atomicAdd(&cur[d >> 7], 1u);
        epk[pos] = ((d & 127u) << 17) | s;
    }
}

// per bucket: degree count + LDS scan -> rowptr/dinv; re-scatter to node-sorted esrc
__global__ __launch_bounds__(256) void k_sort(const unsigned* __restrict__ bbase,
                                              const unsigned* __restrict__ epk,
                                              int* __restrict__ esrc,
                                              unsigned* __restrict__ rowptr,
                                              float* __restrict__ dinv, int N, int E) {
    __shared__ unsigned cnt[128], scn[128];
    const int k = blockIdx.x;
    const int t = threadIdx.x;
    if (t < 128) cnt[t] = 0u;
    __syncthreads();
    const unsigned lo = bbase[k], hi = bbase[k + 1];
    for (unsigned e = lo + t; e < hi; e += 256)
        atomicAdd(&cnt[epk[e] >> 17], 1u);
    __syncthreads();
    unsigned c = (t < 128) ? cnt[t] : 0u;
    if (t < 128) scn[t] = c;
    __syncthreads();
    for (int off = 1; off < 128; off <<= 1) {
        unsigned a = (t < 128 && t >= off) ? scn[t - off] : 0u;
        __syncthreads();
        if (t < 128) scn[t] += a;
        __syncthreads();
    }
    int node = (k << 7) + t;
    if (t < 128) {
        unsigned start = scn[t] - c;
        cnt[t] = start;                            // becomes cursor
        if (node < N) {
            rowptr[node] = lo + start;
            dinv[node] = rsqrtf(1.0f + (float)c);
        }
    }
    if (k == gridDim.x - 1 && t == 0) rowptr[N] = (unsigned)E;
    __syncthreads();
    for (unsigned e = lo + t; e < hi; e += 256) {
        unsigned w = epk[e];
        unsigned pos = atomicAdd(&cnt[w >> 17], 1u);
        esrc[lo + pos] = (int)(w & 0x1FFFFu);
    }
}

// MFMA GEMM: outb[row][col] = bf16( rowscale[row] * sum_k in[row][k]*W[k][col] )
// 4 waves/block, each wave owns a 16-row tile per iteration. W staged via LDS,
// held as bf16 hi+lo B-fragments in VGPRs (f32-accurate weights).
// A-frag (lane l, elem j): row = r0+(l&15), k = 32s+(l>>4)*8+j
// B-frag (lane l, elem j): col = c*16+(l&15), k = 32s+(l>>4)*8+j
// C/D  (lane l, reg j):    col = c*16+(l&15), row = r0+(l>>4)*4+j   [m89]
__global__ __launch_bounds__(256) void k_gemm_mfma(const float* __restrict__ in,
                                                   const float* __restrict__ W,
                                                   const float* __restrict__ rowscale,
                                                   __hip_bfloat16* __restrict__ outb,
                                                   int N) {
    __shared__ float Wl[64 * 64];
    for (int i = threadIdx.x; i < 4096; i += 256) Wl[i] = W[i];
    __syncthreads();
    const int lane = threadIdx.x & 63;
    const int wv   = threadIdx.x >> 6;
    const int lr   = lane & 15;
    const int lg   = lane >> 4;

    short8v bhi[4][2], blo[4][2];
#pragma unroll
    for (int c = 0; c < 4; ++c)
#pragma unroll
        for (int s = 0; s < 2; ++s)
#pragma unroll
            for (int j = 0; j < 8; ++j) {
                float wf = Wl[(32 * s + lg * 8 + j) * 64 + c * 16 + lr];
                unsigned short hi = f2b(wf);
                bhi[c][s][j] = (short)hi;
                blo[c][s][j] = (short)f2b(wf - b2f(hi));
            }

    ushort* outp = reinterpret_cast<ushort*>(outb);
    const int tiles = (N + 15) >> 4;
    for (int t = blockIdx.x * 4 + wv; t < tiles; t += gridDim.x * 4) {
        const int r0 = t << 4;
        const int arow = min(r0 + lr, N - 1);
        const float* ap = in + (size_t)arow * 64 + lg * 8;
        float4 x0 = *reinterpret_cast<const float4*>(ap);
        float4 x1 = *reinterpret_cast<const float4*>(ap + 4);
        float4 x2 = *reinterpret_cast<const float4*>(ap + 32);
        float4 x3 = *reinterpret_cast<const float4*>(ap + 36);
        short8v a0, a1;
        a0[0] = (short)f2b(x0.x); a0[1] = (short)f2b(x0.y);
        a0[2] = (short)f2b(x0.z); a0[3] = (short)f2b(x0.w);
        a0[4] = (short)f2b(x1.x); a0[5] = (short)f2b(x1.y);
        a0[6] = (short)f2b(x1.z); a0[7] = (short)f2b(x1.w);
        a1[0] = (short)f2b(x2.x); a1[1] = (short)f2b(x2.y);
        a1[2] = (short)f2b(x2.z); a1[3] = (short)f2b(x2.w);
        a1[4] = (short)f2b(x3.x); a1[5] = (short)f2b(x3.y);
        a1[6] = (short)f2b(x3.z); a1[7] = (short)f2b(x3.w);

        float4v acc[4];
#pragma unroll
        for (int c = 0; c < 4; ++c) acc[c] = (float4v){0.f, 0.f, 0.f, 0.f};
#pragma unroll
        for (int c = 0; c < 4; ++c) {
            acc[c] = __builtin_amdgcn_mfma_f32_16x16x32_bf16(a0, bhi[c][0], acc[c], 0, 0, 0);
            acc[c] = __builtin_amdgcn_mfma_f32_16x16x32_bf16(a1, bhi[c][1], acc[c], 0, 0, 0);
            acc[c] = __builtin_amdgcn_mfma_f32_16x16x32_bf16(a0, blo[c][0], acc[c], 0, 0, 0);
            acc[c] = __builtin_amdgcn_mfma_f32_16x16x32_bf16(a1, blo[c][1], acc[c], 0, 0, 0);
        }

        const float4 rs4 = *reinterpret_cast<const float4*>(rowscale + min(r0 + lg * 4, N - 4));
#pragma unroll
        for (int j = 0; j < 4; ++j) {
            const int row = r0 + lg * 4 + j;
            if (row < N) {
                const float rs = (&rs4.x)[j];
#pragma unroll
                for (int c = 0; c < 4; ++c)
                    outp[(size_t)row * 64 + c * 16 + lr] = f2b(acc[c][j] * rs);
            }
        }
    }
}

// node-parallel CSR gather on bf16 hs: 16 threads/node, ushort4/thread, unroll 4.
// f32 accumulate; epilogue relu(dinv*sum + bias) written f32.
__global__ __launch_bounds__(256) void k_agg_csr(const __hip_bfloat16* __restrict__ hs,
                                                 const float* __restrict__ dinv,
                                                 const unsigned* __restrict__ rowptr,
                                                 const int* __restrict__ esrc,
                                                 const float* __restrict__ bias,
                                                 float* __restrict__ out, int N) {
    int g = blockIdx.x * 16 + (threadIdx.x >> 4);
    if (g >= N) return;
    int c = (threadIdx.x & 15) * 4;
    const ushort* hb = reinterpret_cast<const ushort*>(hs);
    unsigned k = rowptr[g], end = rowptr[g + 1];
    ushort4 sv = *reinterpret_cast<const ushort4*>(hb + (size_t)g * 64 + c);  // self
    float sx = b2f(sv.x), sy = b2f(sv.y), sz = b2f(sv.z), sw = b2f(sv.w);
    for (; k + 4 <= end; k += 4) {
        int s0 = esrc[k], s1 = esrc[k + 1], s2 = esrc[k + 2], s3 = esrc[k + 3];
        ushort4 a = *reinterpret_cast<const ushort4*>(hb + (size_t)s0 * 64 + c);
        ushort4 b = *reinterpret_cast<const ushort4*>(hb + (size_t)s1 * 64 + c);
        ushort4 d = *reinterpret_cast<const ushort4*>(hb + (size_t)s2 * 64 + c);
        ushort4 e = *reinterpret_cast<const ushort4*>(hb + (size_t)s3 * 64 + c);
        sx += (b2f(a.x) + b2f(b.x)) + (b2f(d.x) + b2f(e.x));
        sy += (b2f(a.y) + b2f(b.y)) + (b2f(d.y) + b2f(e.y));
        sz += (b2f(a.z) + b2f(b.z)) + (b2f(d.z) + b2f(e.z));
        sw += (b2f(a.w) + b2f(b.w)) + (b2f(d.w) + b2f(e.w));
    }
    for (; k < end; ++k) {
        int s = esrc[k];
        ushort4 a = *reinterpret_cast<const ushort4*>(hb + (size_t)s * 64 + c);
        sx += b2f(a.x); sy += b2f(a.y); sz += b2f(a.z); sw += b2f(a.w);
    }
    float di = dinv[g];
    float4 bv = *reinterpret_cast<const float4*>(bias + c);
    float4 o;
    o.x = fmaxf(fmaf(di, sx, bv.x), 0.0f);
    o.y = fmaxf(fmaf(di, sy, bv.y), 0.0f);
    o.z = fmaxf(fmaf(di, sz, bv.z), 0.0f);
    o.w = fmaxf(fmaf(di, sw, bv.w), 0.0f);
    *reinterpret_cast<float4*>(out + (size_t)g * 64 + c) = o;
}

// colsum[j] = sum_rows in[row][j]   (input already rectified+biased)
__global__ __launch_bounds__(256) void k_colsum(const float* __restrict__ in,
                                                float* __restrict__ colsum, int N) {
    const int lane = threadIdx.x & 63;
    const int wave = threadIdx.x >> 6;
    float acc = 0.0f;
    for (int row = blockIdx.x * 4 + wave; row < N; row += gridDim.x * 4)
        acc += in[(size_t)row * 64 + lane];
    __shared__ float red[4][64];
    red[wave][lane] = acc;
    __syncthreads();
    if (wave == 0)
        unsafeAtomicAdd(&colsum[lane],
                        red[0][lane] + red[1][lane] + red[2][lane] + red[3][lane]);
}

// out[j] = (colsum/N) @ Wfc + bfc
__global__ void k_final(const float* __restrict__ colsum, const float* __restrict__ Wfc,
                        const float* __restrict__ bfc, float* __restrict__ out, float invN) {
    int j = threadIdx.x;  // 64 threads
    float acc = 0.0f;
#pragma unroll
    for (int i = 0; i < 64; ++i)
        acc = fmaf(colsum[i] * invN, Wfc[i * 64 + j], acc);
    out[j] = acc + bfc[j];
}

extern "C" void kernel_launch(void* const* d_in, const int* in_sizes, int n_in,
                              void* d_out, int out_size, void* d_ws, size_t ws_size,
                              hipStream_t stream) {
    const float* x   = (const float*)d_in[0];
    const int*   ei  = (const int*)d_in[1];
    const float* W1  = (const float*)d_in[2];
    const float* b1  = (const float*)d_in[3];
    const float* W2  = (const float*)d_in[4];
    const float* b2  = (const float*)d_in[5];
    const float* Wfc = (const float*)d_in[6];
    const float* bfc = (const float*)d_in[7];
    float*       out = (float*)d_out;

    const int N = in_sizes[0] / 64;
    const int E = in_sizes[1] / 2;
    const int* src = ei;       // edge_index[0]
    const int* dst = ei + E;   // edge_index[1]

    const int nbuk  = (N + 127) >> 7;              // 782
    const int chunk = (E + NSB - 1) / NSB;

    char* ws = (char*)d_ws;
    const size_t NB2 = (size_t)N * 64 * sizeof(__hip_bfloat16);   // 12.8 MB (hs)
    const size_t NB4 = (size_t)N * 64 * sizeof(float);            // 25.6 MB
    const size_t N4  = (((size_t)(N + 1) * 4) + 255) & ~(size_t)255;
    const size_t E4  = (((size_t)E * 4) + 255) & ~(size_t)255;
    __hip_bfloat16* bufA = (__hip_bfloat16*)ws;                   // hs (bf16)
    float*    bufB   = (float*)(ws + NB2);                        // agg out (f32)
    unsigned* cntBB  = (unsigned*)ws;              // aliases bufA (dead before GEMM1)
    unsigned* epk    = (unsigned*)(ws + NB2);      // aliases bufB (dead before agg1)
    float*    dinv   = (float*)(ws + NB2 + NB4);
    unsigned* rowptr = (unsigned*)(ws + NB2 + NB4 + N4);
    unsigned* bbase  = (unsigned*)(ws + NB2 + NB4 + 2 * N4);
    unsigned* btot   = (unsigned*)(ws + NB2 + NB4 + 2 * N4 + 4096);
    int*      esrc   = (int*)(ws + NB2 + NB4 + 2 * N4 + 8192);
    float*    csum   = (float*)(ws + NB2 + NB4 + 2 * N4 + 8192 + E4);

    // ---- bucket-CSR build (all per-edge atomics in LDS) ----
    k_bcount<<<NSB, 256, 0, stream>>>(dst, cntBB, E, nbuk, chunk);
    k_block_base<<<nbuk, NSB, 0, stream>>>(cntBB, btot, nbuk);
    k_scan_buckets<<<1, 1024, 0, stream>>>(btot, bbase, csum, nbuk);
    k_bscatter<<<NSB, 256, 0, stream>>>(src, dst, cntBB, bbase, epk, E, nbuk, chunk);
    k_sort<<<nbuk, 256, 0, stream>>>(bbase, epk, esrc, rowptr, dinv, N, E);

    // ---- layer 1 ----
    k_gemm_mfma<<<1024, 256, 0, stream>>>(x, W1, dinv, bufA, N);
    k_agg_csr<<<(N + 15) / 16, 256, 0, stream>>>(bufA, dinv, rowptr, esrc, b1, bufB, N);

    // ---- layer 2 ----
    k_gemm_mfma<<<1024, 256, 0, stream>>>(bufB, W2, dinv, bufA, N);
    k_agg_csr<<<(N + 15) / 16, 256, 0, stream>>>(bufA, dinv, rowptr, esrc, b2, bufB, N);

    // ---- head: mean(h2r) @ Wfc + bfc ----
    k_colsum<<<1024, 256, 0, stream>>>(bufB, csum, N);
    k_final<<<1, 64, 0, stream>>>(csum, Wfc, bfc, out, 1.0f / (float)N);
}

// Round 10
// 187.726 us; speedup vs baseline: 9.4226x; 1.0213x over previous
//
#include <hip/hip_runtime.h>
#include <hip/hip_bf16.h>

// ---------------------------------------------------------------------------
// GCN via bucket-built, node-sorted CSR + MFMA GEMM + fp8 gather payloads.
//   GEMM: hs = fp8_perm( dinv[row] * (in @ W) )  via mfma_f32_16x16x32_bf16,
//         W split W=Whi+Wlo (bf16 pair) -> f32-accurate weights.
//   AGG:  relu( dinv_i*(hs_i + sum_{src->i} hs_src) + bias )
//         layer1 -> h1r (bf16, perm layout); layer2 -> fused column-sum only.
//   out = (colsum/N) @ Wfc + bfc  (mean/GEMM commute; Wfc rows unpermuted)
// Perm layout: stored pos p = 4*lr+c holds orig col c*16+lr, i.e.
//   orig(p) = (p&3)*16 + (p>>2). Makes MFMA epilogue stores contiguous.
// Bucket = 128 consecutive dst nodes; packed edge word (dst&127)<<17|src.
// edge_index arrives int32. All per-edge atomics are LDS-only.
// ---------------------------------------------------------------------------

#define NSB 512  // scatter blocks

typedef __attribute__((ext_vector_type(8))) short short8v;
typedef __attribute__((ext_vector_type(4))) float float4v;
typedef __attribute__((ext_vector_type(2))) float float2v;

__device__ __forceinline__ float b2f(unsigned short u) {
    return __uint_as_float(((unsigned)u) << 16);
}
__device__ __forceinline__ unsigned short f2b(float f) {  // RNE f32->bf16
    unsigned u = __float_as_uint(f);
    return (unsigned short)((u + 0x7fffu + ((u >> 16) & 1u)) >> 16);
}
__device__ __forceinline__ int origcol(int p) { return (p & 3) * 16 + (p >> 2); }

// per-(scatterblock, bucket) histogram; LDS atomics only
__global__ __launch_bounds__(256) void k_bcount(const int* __restrict__ dst,
                                                unsigned* __restrict__ cntBB,
                                                int E, int nbuk, int chunk) {
    __shared__ unsigned hist[1024];
    for (int i = threadIdx.x; i < nbuk; i += 256) hist[i] = 0u;
    __syncthreads();
    int lo = blockIdx.x * chunk, hi = min(E, lo + chunk);
    for (int e = lo + threadIdx.x; e < hi; e += 256)
        atomicAdd(&hist[((unsigned)dst[e]) >> 7], 1u);
    __syncthreads();
    for (int i = threadIdx.x; i < nbuk; i += 256)
        cntBB[(size_t)blockIdx.x * nbuk + i] = hist[i];
}

// per bucket k: exclusive scan of cntBB[t][k] over t (in place) + btot[k]=total
__global__ __launch_bounds__(NSB) void k_block_base(unsigned* __restrict__ cntBB,
                                                    unsigned* __restrict__ btot,
                                                    int nbuk) {
    __shared__ unsigned s[NSB];
    int k = blockIdx.x;
    int t = threadIdx.x;
    unsigned v = cntBB[(size_t)t * nbuk + k];
    s[t] = v;
    __syncthreads();
    for (int off = 1; off < NSB; off <<= 1) {
        unsigned a = (t >= off) ? s[t - off] : 0u;
        __syncthreads();
        s[t] += a;
        __syncthreads();
    }
    cntBB[(size_t)t * nbuk + k] = s[t] - v;       // local exclusive
    if (t == NSB - 1) btot[k] = s[NSB - 1];
}

// bbase = exclusive scan of btot; also zero csum and build permuted biases
__global__ __launch_bounds__(1024) void k_scan_buckets(const unsigned* __restrict__ btot,
                                                       unsigned* __restrict__ bbase,
                                                       float* __restrict__ csum,
                                                       const float* __restrict__ b1,
                                                       const float* __restrict__ b2,
                                                       float* __restrict__ b1p,
                                                       float* __restrict__ b2p,
                                                       int nbuk) {
    __shared__ unsigned s[1024];
    int k = threadIdx.x;
    if (k < 64) csum[k] = 0.0f;
    else if (k < 128) b1p[k - 64] = b1[origcol(k - 64)];
    else if (k < 192) b2p[k - 128] = b2[origcol(k - 128)];
    unsigned v = (k < nbuk) ? btot[k] : 0u;
    s[k] = v;
    __syncthreads();
    for (int off = 1; off < 1024; off <<= 1) {
        unsigned a = (k >= off) ? s[k - off] : 0u;
        __syncthreads();
        s[k] += a;
        __syncthreads();
    }
    if (k < nbuk) bbase[k] = s[k] - v;
    if (k == 0) bbase[nbuk] = s[1023];            // = E
}

// scatter packed edges into bucket segments; cursors in LDS
__global__ __launch_bounds__(256) void k_bscatter(const int* __restrict__ src,
                                                  const int* __restrict__ dst,
                                                  const unsigned* __restrict__ cntBB,
                                                  const unsigned* __restrict__ bbase,
                                                  unsigned* __restrict__ epk,
                                                  int E, int nbuk, int chunk) {
    __shared__ unsigned cur[1024];
    for (int i = threadIdx.x; i < nbuk; i += 256)
        cur[i] = bbase[i] + cntBB[(size_t)blockIdx.x * nbuk + i];
    __syncthreads();
    int lo = blockIdx.x * chunk, hi = min(E, lo + chunk);
    for (int e = lo + threadIdx.x; e < hi; e += 256) {
        unsigned d = (unsigned)dst[e];
        unsigned s = (unsigned)src[e];
        unsigned pos = atomicAdd(&cur[d >> 7], 1u);
        epk[pos] = ((d & 127u) << 17) | s;
    }
}

// per bucket: degree count + LDS scan -> rowptr/dinv; re-scatter to node-sorted esrc
__global__ __launch_bounds__(256) void k_sort(const unsigned* __restrict__ bbase,
                                              const unsigned* __restrict__ epk,
                                              int* __restrict__ esrc,
                                              unsigned* __restrict__ rowptr,
                                              float* __restrict__ dinv, int N, int E) {
    __shared__ unsigned cnt[128], scn[128];
    const int k = blockIdx.x;
    const int t = threadIdx.x;
    if (t < 128) cnt[t] = 0u;
    __syncthreads();
    const unsigned lo = bbase[k], hi = bbase[k + 1];
    for (unsigned e = lo + t; e < hi; e += 256)
        atomicAdd(&cnt[epk[e] >> 17], 1u);
    __syncthreads();
    unsigned c = (t < 128) ? cnt[t] : 0u;
    if (t < 128) scn[t] = c;
    __syncthreads();
    for (int off = 1; off < 128; off <<= 1) {
        unsigned a = (t < 128 && t >= off) ? scn[t - off] : 0u;
        __syncthreads();
        if (t < 128) scn[t] += a;
        __syncthreads();
    }
    int node = (k << 7) + t;
    if (t < 128) {
        unsigned start = scn[t] - c;
        cnt[t] = start;                            // becomes cursor
        if (node < N) {
            rowptr[node] = lo + start;
            dinv[node] = rsqrtf(1.0f + (float)c);
        }
    }
    if (k == gridDim.x - 1 && t == 0) rowptr[N] = (unsigned)E;
    __syncthreads();
    for (unsigned e = lo + t; e < hi; e += 256) {
        unsigned w = epk[e];
        unsigned pos = atomicAdd(&cnt[w >> 17], 1u);
        esrc[lo + pos] = (int)(w & 0x1FFFFu);
    }
}

// MFMA GEMM -> fp8 perm output.
// AIN=0: in is f32, orig col layout (x). AIN=1: in is bf16, perm layout (h1r).
// W k-index permuted to match A's storage order. W=Whi+Wlo f32-accurate.
// A-frag (lane l, elem j): row=r0+(l&15), stored-k = 32s+(l>>4)*8+j
// C/D  (lane l, reg j):    col=c*16+(l&15), row=r0+(l>>4)*4+j   [m89]
template <int AIN>
__global__ __launch_bounds__(256) void k_gemm_mfma(const void* __restrict__ in,
                                                   const float* __restrict__ W,
                                                   const float* __restrict__ rowscale,
                                                   unsigned* __restrict__ outp,
                                                   int N) {
    __shared__ float Wl[64 * 64];
    for (int i = threadIdx.x; i < 4096; i += 256) Wl[i] = W[i];
    __syncthreads();
    const int lane = threadIdx.x & 63;
    const int wv   = threadIdx.x >> 6;
    const int lr   = lane & 15;
    const int lg   = lane >> 4;

    short8v bhi[4][2], blo[4][2];
#pragma unroll
    for (int c = 0; c < 4; ++c)
#pragma unroll
        for (int s = 0; s < 2; ++s)
#pragma unroll
            for (int j = 0; j < 8; ++j) {
                int p = 32 * s + lg * 8 + j;           // stored-k position
                int k = AIN ? origcol(p) : p;          // orig weight row
                float wf = Wl[k * 64 + c * 16 + lr];
                unsigned short hi = f2b(wf);
                bhi[c][s][j] = (short)hi;
                blo[c][s][j] = (short)f2b(wf - b2f(hi));
            }

    const int tiles = (N + 15) >> 4;
    for (int t = blockIdx.x * 4 + wv; t < tiles; t += gridDim.x * 4) {
        const int r0 = t << 4;
        const int arow = min(r0 + lr, N - 1);
        short8v a0, a1;
        if (AIN == 0) {
            const float* ap = (const float*)in + (size_t)arow * 64 + lg * 8;
            float4 x0 = *reinterpret_cast<const float4*>(ap);
            float4 x1 = *reinterpret_cast<const float4*>(ap + 4);
            float4 x2 = *reinterpret_cast<const float4*>(ap + 32);
            float4 x3 = *reinterpret_cast<const float4*>(ap + 36);
            a0[0] = (short)f2b(x0.x); a0[1] = (short)f2b(x0.y);
            a0[2] = (short)f2b(x0.z); a0[3] = (short)f2b(x0.w);
            a0[4] = (short)f2b(x1.x); a0[5] = (short)f2b(x1.y);
            a0[6] = (short)f2b(x1.z); a0[7] = (short)f2b(x1.w);
            a1[0] = (short)f2b(x2.x); a1[1] = (short)f2b(x2.y);
            a1[2] = (short)f2b(x2.z); a1[3] = (short)f2b(x2.w);
            a1[4] = (short)f2b(x3.x); a1[5] = (short)f2b(x3.y);
            a1[6] = (short)f2b(x3.z); a1[7] = (short)f2b(x3.w);
        } else {
            const ushort* ar = (const ushort*)in + (size_t)arow * 64;
            a0 = *reinterpret_cast<const short8v*>(ar + lg * 8);
            a1 = *reinterpret_cast<const short8v*>(ar + 32 + lg * 8);
        }

        float4v acc[4];
#pragma unroll
        for (int c = 0; c < 4; ++c) acc[c] = (float4v){0.f, 0.f, 0.f, 0.f};
#pragma unroll
        for (int c = 0; c < 4; ++c) {
            acc[c] = __builtin_amdgcn_mfma_f32_16x16x32_bf16(a0, bhi[c][0], acc[c], 0, 0, 0);
            acc[c] = __builtin_amdgcn_mfma_f32_16x16x32_bf16(a1, bhi[c][1], acc[c], 0, 0, 0);
            acc[c] = __builtin_amdgcn_mfma_f32_16x16x32_bf16(a0, blo[c][0], acc[c], 0, 0, 0);
            acc[c] = __builtin_amdgcn_mfma_f32_16x16x32_bf16(a1, blo[c][1], acc[c], 0, 0, 0);
        }

        const float4 rs4 = *reinterpret_cast<const float4*>(rowscale + min(r0 + lg * 4, N - 4));
#pragma unroll
        for (int j = 0; j < 4; ++j) {
            const int row = r0 + lg * 4 + j;
            if (row < N) {
                const float rs = (&rs4.x)[j];
                int pk = __builtin_amdgcn_cvt_pk_fp8_f32(acc[0][j] * rs, acc[1][j] * rs, 0, false);
                pk = __builtin_amdgcn_cvt_pk_fp8_f32(acc[2][j] * rs, acc[3][j] * rs, pk, true);
                outp[(size_t)row * 16 + lr] = (unsigned)pk;   // perm: bytes c=0..3 at dword lr
            }
        }
    }
}

// node-parallel CSR gather on fp8 hs (perm layout): 16 threads/node, u32/thread.
// MODE 0: write relu(dinv*sum+biasp) as bf16 perm rows (h1r).
// MODE 1: accumulate relu(...) into csum (fused head); no matrix write.
template <int MODE>
__global__ __launch_bounds__(256) void k_agg_csr(const unsigned char* __restrict__ hs,
                                                 const float* __restrict__ dinv,
                                                 const unsigned* __restrict__ rowptr,
                                                 const int* __restrict__ esrc,
                                                 const float* __restrict__ biasp,
                                                 ushort* __restrict__ outr,
                                                 float* __restrict__ csum, int N) {
    const int c = threadIdx.x & 15;
    const int grp = threadIdx.x >> 4;
    const unsigned* hw = reinterpret_cast<const unsigned*>(hs);
    float4 cs = {0.f, 0.f, 0.f, 0.f};
    const float4 bv = *reinterpret_cast<const float4*>(biasp + 4 * c);
    for (int g = blockIdx.x * 16 + grp; g < N; g += gridDim.x * 16) {
        unsigned k = rowptr[g], end = rowptr[g + 1];
        unsigned su = hw[(size_t)g * 16 + c];                 // self row
        float2v slo = __builtin_amdgcn_cvt_pk_f32_fp8((int)su, false);
        float2v shi = __builtin_amdgcn_cvt_pk_f32_fp8((int)su, true);
        float sx = slo[0], sy = slo[1], sz = shi[0], sw = shi[1];
        for (; k + 4 <= end; k += 4) {
            int s0 = esrc[k], s1 = esrc[k + 1], s2 = esrc[k + 2], s3 = esrc[k + 3];
            unsigned u0 = hw[(size_t)s0 * 16 + c];
            unsigned u1 = hw[(size_t)s1 * 16 + c];
            unsigned u2 = hw[(size_t)s2 * 16 + c];
            unsigned u3 = hw[(size_t)s3 * 16 + c];
            float2v l0 = __builtin_amdgcn_cvt_pk_f32_fp8((int)u0, false);
            float2v h0 = __builtin_amdgcn_cvt_pk_f32_fp8((int)u0, true);
            float2v l1 = __builtin_amdgcn_cvt_pk_f32_fp8((int)u1, false);
            float2v h1 = __builtin_amdgcn_cvt_pk_f32_fp8((int)u1, true);
            float2v l2 = __builtin_amdgcn_cvt_pk_f32_fp8((int)u2, false);
            float2v h2 = __builtin_amdgcn_cvt_pk_f32_fp8((int)u2, true);
            float2v l3 = __builtin_amdgcn_cvt_pk_f32_fp8((int)u3, false);
            float2v h3 = __builtin_amdgcn_cvt_pk_f32_fp8((int)u3, true);
            sx += (l0[0] + l1[0]) + (l2[0] + l3[0]);
            sy += (l0[1] + l1[1]) + (l2[1] + l3[1]);
            sz += (h0[0] + h1[0]) + (h2[0] + h3[0]);
            sw += (h0[1] + h1[1]) + (h2[1] + h3[1]);
        }
        for (; k < end; ++k) {
            unsigned u = hw[(size_t)esrc[k] * 16 + c];
            float2v lo = __builtin_amdgcn_cvt_pk_f32_fp8((int)u, false);
            float2v hi = __builtin_amdgcn_cvt_pk_f32_fp8((int)u, true);
            sx += lo[0]; sy += lo[1]; sz += hi[0]; sw += hi[1];
        }
        const float di = dinv[g];
        float4 o;
        o.x = fmaxf(fmaf(di, sx, bv.x), 0.0f);
        o.y = fmaxf(fmaf(di, sy, bv.y), 0.0f);
        o.z = fmaxf(fmaf(di, sz, bv.z), 0.0f);
        o.w = fmaxf(fmaf(di, sw, bv.w), 0.0f);
        if (MODE == 0) {
            ushort4 hv;
            hv.x = f2b(o.x); hv.y = f2b(o.y); hv.z = f2b(o.z); hv.w = f2b(o.w);
            *reinterpret_cast<ushort4*>(outr + (size_t)g * 64 + 4 * c) = hv;
        } else {
            cs.x += o.x; cs.y += o.y; cs.z += o.z; cs.w += o.w;
        }
    }
    if (MODE == 1) {
        __shared__ float red[16][68];
        red[grp][4 * c + 0] = cs.x;
        red[grp][4 * c + 1] = cs.y;
        red[grp][4 * c + 2] = cs.z;
        red[grp][4 * c + 3] = cs.w;
        __syncthreads();
        int t = threadIdx.x;
        if (t < 64) {
            float s = 0.f;
#pragma unroll
            for (int g = 0; g < 16; ++g) s += red[g][t];
            unsafeAtomicAdd(&csum[t], s);
        }
    }
}

// out[j] = (csum/N) @ Wfc + bfc, unpermuting csum positions
__global__ void k_final(const float* __restrict__ csum, const float* __restrict__ Wfc,
                        const float* __restrict__ bfc, float* __restrict__ out, float invN) {
    int j = threadIdx.x;  // 64 threads
    float acc = 0.0f;
#pragma unroll
    for (int p = 0; p < 64; ++p)
        acc = fmaf(csum[p] * invN, Wfc[origcol(p) * 64 + j], acc);
    out[j] = acc + bfc[j];
}

extern "C" void kernel_launch(void* const* d_in, const int* in_sizes, int n_in,
                              void* d_out, int out_size, void* d_ws, size_t ws_size,
                              hipStream_t stream) {
    const float* x   = (const float*)d_in[0];
    const int*   ei  = (const int*)d_in[1];
    const float* W1  = (const float*)d_in[2];
    const float* b1  = (const float*)d_in[3];
    const float* W2  = (const float*)d_in[4];
    const float* b2  = (const float*)d_in[5];
    const float* Wfc = (const float*)d_in[6];
    const float* bfc = (const float*)d_in[7];
    float*       out = (float*)d_out;

    const int N = in_sizes[0] / 64;
    const int E = in_sizes[1] / 2;
    const int* src = ei;       // edge_index[0]
    const int* dst = ei + E;   // edge_index[1]

    const int nbuk  = (N + 127) >> 7;              // 782
    const int chunk = (E + NSB - 1) / NSB;

    char* ws = (char*)d_ws;
    const size_t NBH = (size_t)N * 64;                          // 6.4 MB fp8 hs
    const size_t NBR = (size_t)N * 64 * 2;                      // 12.8 MB bf16 h1r
    const size_t N4  = (((size_t)(N + 1) * 4) + 255) & ~(size_t)255;
    unsigned char* hsbuf = (unsigned char*)ws;                  // fp8 (both layers)
    ushort*   h1r    = (ushort*)(ws + NBH);                     // bf16 perm
    unsigned* epk    = (unsigned*)ws;              // aliases hsbuf (dead before GEMM1)
    unsigned* cntBB  = (unsigned*)(ws + NBH);      // aliases h1r (dead before agg1)
    float*    dinv   = (float*)(ws + NBH + NBR);
    unsigned* rowptr = (unsigned*)(ws + NBH + NBR + N4);
    unsigned* bbase  = (unsigned*)(ws + NBH + NBR + 2 * N4);
    unsigned* btot   = (unsigned*)(ws + NBH + NBR + 2 * N4 + 4096);
    float*    csum   = (float*)(ws + NBH + NBR + 2 * N4 + 8192);
    float*    b1p    = csum + 64;
    float*    b2p    = csum + 128;
    int*      esrc   = (int*)(ws + NBH + NBR + 2 * N4 + 12288);

    // ---- bucket-CSR build (all per-edge atomics in LDS) ----
    k_bcount<<<NSB, 256, 0, stream>>>(dst, cntBB, E, nbuk, chunk);
    k_block_base<<<nbuk, NSB, 0, stream>>>(cntBB, btot, nbuk);
    k_scan_buckets<<<1, 1024, 0, stream>>>(btot, bbase, csum, b1, b2, b1p, b2p, nbuk);
    k_bscatter<<<NSB, 256, 0, stream>>>(src, dst, cntBB, bbase, epk, E, nbuk, chunk);
    k_sort<<<nbuk, 256, 0, stream>>>(bbase, epk, esrc, rowptr, dinv, N, E);

    // ---- layer 1: GEMM (f32 in) -> fp8 hs; agg -> bf16 h1r ----
    k_gemm_mfma<0><<<1024, 256, 0, stream>>>(x, W1, dinv, (unsigned*)hsbuf, N);
    k_agg_csr<0><<<(N + 15) / 16, 256, 0, stream>>>(hsbuf, dinv, rowptr, esrc, b1p,
                                                    h1r, nullptr, N);

    // ---- layer 2: GEMM (bf16 perm in) -> fp8 hs; agg fused with column-sum ----
    k_gemm_mfma<1><<<1024, 256, 0, stream>>>(h1r, W2, dinv, (unsigned*)hsbuf, N);
    k_agg_csr<1><<<2048, 256, 0, stream>>>(hsbuf, dinv, rowptr, esrc, b2p,
                                           nullptr, csum, N);

    // ---- head ----
    k_final<<<1, 64, 0, stream>>>(csum, Wfc, bfc, out, 1.0f / (float)N);
}